// Round 2
// baseline (345.419 us; speedup 1.0000x reference)
//
#include <hip/hip_runtime.h>
#include <hip/hip_bf16.h>

// Shapes (fixed): B=1, S=2048, HID=2048, NH=16, NKV=4, HD=128
// Inputs: fp32. Output: fp32. Internal compute: bf16 MFMA, fp32 accumulate.
typedef __bf16 bf16_t;
typedef __attribute__((ext_vector_type(8))) __bf16 bf16x8;
typedef __attribute__((ext_vector_type(4))) __bf16 bf16x4;
typedef __attribute__((ext_vector_type(4))) float f32x4;

#define S_LEN 2048
#define HID 2048
#define NH 16
#define NKV 4
#define HD 128

__device__ __forceinline__ void gll16(const bf16_t* g, bf16_t* l) {
    __builtin_amdgcn_global_load_lds(
        (const __attribute__((address_space(1))) unsigned int*)g,
        (__attribute__((address_space(3))) unsigned int*)l, 16, 0, 0);
}

__device__ __forceinline__ bf16x8 cvt2x4(float4 a, float4 b) {
    bf16x8 o;
    o[0]=(bf16_t)a.x; o[1]=(bf16_t)a.y; o[2]=(bf16_t)a.z; o[3]=(bf16_t)a.w;
    o[4]=(bf16_t)b.x; o[5]=(bf16_t)b.y; o[6]=(bf16_t)b.z; o[7]=(bf16_t)b.w;
    return o;
}

// ---------------------------------------------------------------------------
__global__ __launch_bounds__(256) void cvt_f32_bf16(const float* __restrict__ in,
                                                    bf16_t* __restrict__ out, int n)
{
    int i = (blockIdx.x * 256 + threadIdx.x) * 8;
    if (i >= n) return;
    float4 a = *(const float4*)&in[i];
    float4 b = *(const float4*)&in[i + 4];
    *(bf16x8*)&out[i] = cvt2x4(a, b);
}

// Fused weight conversion: [wq | wk | wv] fp32 -> contiguous bf16 (3072 x 2048)
__global__ __launch_bounds__(256) void cvt_w3(const float* __restrict__ wq,
                                              const float* __restrict__ wk,
                                              const float* __restrict__ wv,
                                              bf16_t* __restrict__ out)
{
    int i = (blockIdx.x * 256 + threadIdx.x) * 8;
    const float* src; int off;
    if (i < 4 * 1024 * 1024)      { src = wq; off = i; }
    else if (i < 5 * 1024 * 1024) { src = wk; off = i - 4 * 1024 * 1024; }
    else                          { src = wv; off = i - 5 * 1024 * 1024; }
    float4 a = *(const float4*)&src[off];
    float4 b = *(const float4*)&src[off + 4];
    *(bf16x8*)&out[i] = cvt2x4(a, b);
}

// ---------------------------------------------------------------------------
// m97-recipe NT GEMM, tile 128x64. QKV grid 48x16=768=3/CU, out grid
// 32x16=512=2/CU (both exactly divisible -> inter-block latency hiding).
// MODE 0: C fp32 row-major. MODE 1: qkv routing (C=q bf16 / Ck / Cvt^T).
// ---------------------------------------------------------------------------
template<int MODE, typename CT>
__global__ __launch_bounds__(256, 4) void gemm128x64(
    const bf16_t* __restrict__ A, const bf16_t* __restrict__ B,
    CT* __restrict__ C, bf16_t* __restrict__ CkP, bf16_t* __restrict__ CvtP,
    int N, int K)
{
    __shared__ __align__(16) bf16_t sA[128 * 64];   // 16 KB
    __shared__ __align__(16) bf16_t sB[64 * 64];    //  8 KB

    const int tid = threadIdx.x, lane = tid & 63, wave = tid >> 6;
    const int l16 = lane & 15, quad = lane >> 4;
    const int m0 = blockIdx.y * 128, n0 = blockIdx.x * 64;
    const int wm = (wave >> 1) * 64, wn = (wave & 1) * 32;

    const bf16_t* gA[4]; const bf16_t* gB[2];
    bf16_t* lA[4]; bf16_t* lB[2];
#pragma unroll
    for (int t = 0; t < 4; t++) {
        int p = (wave * 4 + t) * 64 + lane;
        int row = p >> 3;
        int lc = (p & 7) ^ (row & 7);
        gA[t] = A + (size_t)(m0 + row) * K + lc * 8;
        lA[t] = &sA[(wave * 4 + t) * 512];
    }
#pragma unroll
    for (int t = 0; t < 2; t++) {
        int p = (wave * 2 + t) * 64 + lane;
        int row = p >> 3;
        int lc = (p & 7) ^ (row & 7);
        gB[t] = B + (size_t)(n0 + row) * K + lc * 8;
        lB[t] = &sB[(wave * 2 + t) * 512];
    }

    int offA[2][4], offB[2][2];
#pragma unroll
    for (int kc = 0; kc < 2; kc++) {
#pragma unroll
        for (int i = 0; i < 4; i++) {
            int rm = wm + i * 16 + l16;
            offA[kc][i] = rm * 64 + (((kc * 4 + quad) ^ (rm & 7)) * 8);
        }
#pragma unroll
        for (int j = 0; j < 2; j++) {
            int rn = wn + j * 16 + l16;
            offB[kc][j] = rn * 64 + (((kc * 4 + quad) ^ (rn & 7)) * 8);
        }
    }

    f32x4 acc[4][2] = {};

    for (int k0 = 0; k0 < K; k0 += 64) {
        __syncthreads();
#pragma unroll
        for (int t = 0; t < 4; t++) { gll16(gA[t], lA[t]); gA[t] += 64; }
#pragma unroll
        for (int t = 0; t < 2; t++) { gll16(gB[t], lB[t]); gB[t] += 64; }
        __syncthreads();

#pragma unroll
        for (int kc = 0; kc < 2; kc++) {
            bf16x8 af[4], bfv[2];
#pragma unroll
            for (int i = 0; i < 4; i++) af[i] = *(bf16x8*)&sA[offA[kc][i]];
#pragma unroll
            for (int j = 0; j < 2; j++) bfv[j] = *(bf16x8*)&sB[offB[kc][j]];
#pragma unroll
            for (int i = 0; i < 4; i++)
#pragma unroll
                for (int j = 0; j < 2; j++)
                    acc[i][j] = __builtin_amdgcn_mfma_f32_16x16x32_bf16(af[i], bfv[j], acc[i][j], 0, 0, 0);
        }
    }

#pragma unroll
    for (int i = 0; i < 4; i++) {
        int rowb = m0 + wm + i * 16 + quad * 4;
#pragma unroll
        for (int j = 0; j < 2; j++) {
            int col = n0 + wn + j * 16 + l16;
#pragma unroll
            for (int r = 0; r < 4; r++) {
                float v = acc[i][j][r];
                int row = rowb + r;
                if (MODE == 0) {
                    C[(size_t)row * N + col] = (CT)v;
                } else {
                    if (col < 2048)      C[(size_t)row * 2048 + col] = (CT)v;
                    else if (col < 2560) CkP[(size_t)row * 512 + (col - 2048)] = (bf16_t)v;
                    else                 CvtP[(size_t)(col - 2560) * S_LEN + row] = (bf16_t)v;
                }
            }
        }
    }
}

// ---------------------------------------------------------------------------
// Fused RoPE over q (16 heads) and k (4 heads): grid (S, 5), block 128.
// ---------------------------------------------------------------------------
__global__ void rope_all(bf16_t* __restrict__ Qh, bf16_t* __restrict__ Kh,
                         const float* __restrict__ cosb, const float* __restrict__ sinb)
{
    int s = blockIdx.x;
    int grp = blockIdx.y;
    int sub = threadIdx.x >> 5;
    int i = threadIdx.x & 31;
    bf16_t* row = (grp < 4) ? (Qh + ((size_t)s * NH + grp * 4 + sub) * HD)
                            : (Kh + ((size_t)s * NKV + sub) * HD);
    float x0 = (float)row[2 * i];
    float x1 = (float)row[2 * i + 1];
    float p0 = (float)row[64 + 2 * i];
    float p1 = (float)row[64 + 2 * i + 1];
    float c0 = cosb[s * HD + 2 * i];
    float c1 = cosb[s * HD + 2 * i + 1];
    float n0 = sinb[s * HD + 2 * i];
    float n1 = sinb[s * HD + 2 * i + 1];
    float r0 = -x1, r1 = x0;
    row[2 * i]          = (bf16_t)(r0 * c0 + p0 * n0);
    row[2 * i + 1]      = (bf16_t)(r1 * c1 + p1 * n1);
    row[64 + 2 * i]     = (bf16_t)(-r0 * n0 + p0 * c0);
    row[64 + 2 * i + 1] = (bf16_t)(-r1 * n1 + p1 * c1);
}

// ---------------------------------------------------------------------------
// Flash attention v9. Changes vs v8 (counters: MfmaUtil 14% / VALU 16% /
// Occ 10.5% -> latency + triangle imbalance):
//  1. Balanced k-chunks: splits(qt)=1+qt/8, every chunk <= 8 tiles.
//     Grid (80 chunks, 4 kvh) = 320 blocks; partial slot per chunk.
//  2. LDS 90->71 KB (K single-buffered, V dbuf) -> 2 blocks/CU co-resident
//     -> 4 waves/SIMD on doubled CUs. Per iter: QK -> barrier A -> stage
//     next K+V (overlaps exp/PV) -> barrier B.
//  3. s_setprio(1) around MFMA clusters (T5).
// Wave dataflow (16 q-rows x 2 heads, swapped QK, wave-private sP,
// unnormalized partials) is unchanged from the verified v8.
// ---------------------------------------------------------------------------
__global__ __launch_bounds__(512, 4) void flash_attn9(
    const bf16_t* __restrict__ Q,   // S x (NH*HD)
    const bf16_t* __restrict__ Kb,  // S x (NKV*HD)
    const bf16_t* __restrict__ VT,  // (NKV*HD) x S
    bf16_t* __restrict__ OpD,       // partial slots 0..255 (d_out, 64KB each)
    bf16_t* __restrict__ OpX,       // partial slots 256..319 (ws)
    float* __restrict__ lpart,      // 320 x 256 fp32
    int S)
{
    __shared__ __align__(16) bf16_t sK[64 * 136];      // 17.4 KB (single buf)
    __shared__ __align__(16) bf16_t sVT[2][128 * 72];  // 36.9 KB (dbuf)
    __shared__ __align__(16) bf16_t sP[8][16 * 72];    // 18.4 KB, wave-private

    const int c   = blockIdx.x;          // chunk id 0..79
    const int kvh = blockIdx.y;
    // decode chunk -> (qt, ci): splits(qt) = 1 + qt/8
    int qt = 0, cb = 0;
    while (cb + 1 + (qt >> 3) <= c) { cb += 1 + (qt >> 3); qt++; }
    const int ci     = c - cb;
    const int splits = 1 + (qt >> 3);
    const int ntiles = qt + 1;
    const int tb = (ci * ntiles) / splits;
    const int te = ((ci + 1) * ntiles) / splits;

    const int q0  = qt * 64;
    const int tid = threadIdx.x, lane = tid & 63, wave = tid >> 6;
    const int l16 = lane & 15, quad = lane >> 4;
    const int rowg = wave & 3;                    // q-row group
    const int h0   = kvh * 4 + (wave >> 2) * 2;   // this wave's 2 heads
    const float scale = 0.08838834764831845f;     // 1/sqrt(128)

    const int qrow = q0 + rowg * 16 + l16;

    // Q fragments: 2 heads (B-operand of swapped QK)
    bf16x8 qf[2][4];
#pragma unroll
    for (int h = 0; h < 2; h++)
#pragma unroll
        for (int cc = 0; cc < 4; cc++)
            qf[h][cc] = *(const bf16x8*)&Q[(size_t)qrow * HID + (h0 + h) * HD + cc * 32 + quad * 8];

    f32x4 oacc[2][8] = {};
    float lsum[2] = {0.f, 0.f};

    // staging: 1024 16B-chunks per tile, 512 threads -> 2 chunks each
    int krow[2], kcol[2], vrow[2], vcol[2];
#pragma unroll
    for (int it = 0; it < 2; it++) {
        int cc = tid + 512 * it;
        krow[it] = cc >> 4; kcol[it] = (cc & 15) * 8;
        vrow[it] = cc >> 3; vcol[it] = (cc & 7) * 8;
    }

    // prologue: tile tb -> regs -> sK / sVT[0]; prefetch tb+1 into regs
    bf16x8 kpre[2], vpre[2];
#pragma unroll
    for (int it = 0; it < 2; it++) {
        kpre[it] = *(const bf16x8*)&Kb[(size_t)(tb * 64 + krow[it]) * (NKV * HD) + kvh * HD + kcol[it]];
        vpre[it] = *(const bf16x8*)&VT[((size_t)kvh * HD + vrow[it]) * S + tb * 64 + vcol[it]];
    }
#pragma unroll
    for (int it = 0; it < 2; it++) {
        *(bf16x8*)&sK[krow[it] * 136 + kcol[it]] = kpre[it];
        *(bf16x8*)&sVT[0][vrow[it] * 72 + vcol[it]] = vpre[it];
    }
    if (tb + 1 < te) {
        const int t1 = (tb + 1) * 64;
#pragma unroll
        for (int it = 0; it < 2; it++) {
            kpre[it] = *(const bf16x8*)&Kb[(size_t)(t1 + krow[it]) * (NKV * HD) + kvh * HD + kcol[it]];
            vpre[it] = *(const bf16x8*)&VT[((size_t)kvh * HD + vrow[it]) * S + t1 + vcol[it]];
        }
    }
    __syncthreads();

    int sel = 0;
    for (int kt = tb; kt < te; kt++) {
        const int t0 = kt * 64;
        const int ns = sel ^ 1;

        // ---- QK^T (swapped): nt outer, kf read once, 2 heads share it ----
        f32x4 sc[2][4];   // [h][nt]
        __builtin_amdgcn_s_setprio(1);
#pragma unroll
        for (int nt = 0; nt < 4; nt++) {
            bf16x8 kf[4];
#pragma unroll
            for (int cc = 0; cc < 4; cc++)
                kf[cc] = *(bf16x8*)&sK[(nt * 16 + l16) * 136 + cc * 32 + quad * 8];
#pragma unroll
            for (int h = 0; h < 2; h++) {
                f32x4 d = {};
#pragma unroll
                for (int cc = 0; cc < 4; cc++)
                    d = __builtin_amdgcn_mfma_f32_16x16x32_bf16(kf[cc], qf[h][cc], d, 0, 0, 0);
                sc[h][nt] = d;
            }
        }
        __builtin_amdgcn_s_setprio(0);

        __syncthreads();   // A: all waves done reading sK (tile kt)

        // stage tile kt+1: K into sK (freed above), V into sVT[ns].
        // These ds_writes overlap the exp + PV work below.
        if (kt + 1 < te) {
#pragma unroll
            for (int it = 0; it < 2; it++) {
                *(bf16x8*)&sK[krow[it] * 136 + kcol[it]] = kpre[it];
                *(bf16x8*)&sVT[ns][vrow[it] * 72 + vcol[it]] = vpre[it];
            }
            if (kt + 2 < te) {
                const int t2 = t0 + 128;
#pragma unroll
                for (int it = 0; it < 2; it++) {
                    kpre[it] = *(const bf16x8*)&Kb[(size_t)(t2 + krow[it]) * (NKV * HD) + kvh * HD + kcol[it]];
                    vpre[it] = *(const bf16x8*)&VT[((size_t)kvh * HD + vrow[it]) * S + t2 + vcol[it]];
                }
            }
        }

        // ---- exp + packed P write + A-frag read (wave-private sP) ----
        bf16x8 pa[2][2];
        if (kt == qt) {
#pragma unroll
            for (int h = 0; h < 2; h++) {
#pragma unroll
                for (int nt = 0; nt < 4; nt++) {
                    const int tbk = t0 + nt * 16 + quad * 4;
                    bf16x4 pk;
#pragma unroll
                    for (int r = 0; r < 4; r++) {
                        float p = (tbk + r <= qrow) ? __expf(sc[h][nt][r] * scale) : 0.0f;
                        lsum[h] += p;
                        pk[r] = (bf16_t)p;
                    }
                    *(bf16x4*)&sP[wave][l16 * 72 + nt * 16 + quad * 4] = pk;
                }
#pragma unroll
                for (int kc = 0; kc < 2; kc++)
                    pa[h][kc] = *(bf16x8*)&sP[wave][l16 * 72 + kc * 32 + quad * 8];
            }
        } else {
#pragma unroll
            for (int h = 0; h < 2; h++) {
#pragma unroll
                for (int nt = 0; nt < 4; nt++) {
                    bf16x4 pk;
#pragma unroll
                    for (int r = 0; r < 4; r++) {
                        float p = __expf(sc[h][nt][r] * scale);
                        lsum[h] += p;
                        pk[r] = (bf16_t)p;
                    }
                    *(bf16x4*)&sP[wave][l16 * 72 + nt * 16 + quad * 4] = pk;
                }
#pragma unroll
                for (int kc = 0; kc < 2; kc++)
                    pa[h][kc] = *(bf16x8*)&sP[wave][l16 * 72 + kc * 32 + quad * 8];
            }
        }

        // ---- PV: dt outer, vf read once, 2 heads share it ----
        __builtin_amdgcn_s_setprio(1);
#pragma unroll
        for (int dt = 0; dt < 8; dt++)
#pragma unroll
            for (int kc = 0; kc < 2; kc++) {
                bf16x8 vf = *(bf16x8*)&sVT[sel][(dt * 16 + l16) * 72 + kc * 32 + quad * 8];
#pragma unroll
                for (int h = 0; h < 2; h++)
                    oacc[h][dt] = __builtin_amdgcn_mfma_f32_16x16x32_bf16(pa[h][kc], vf, oacc[h][dt], 0, 0, 0);
            }
        __builtin_amdgcn_s_setprio(0);

        __syncthreads();   // B: sK/sVT[ns] writes visible; sVT[sel] reads done
        sel = ns;
    }

    // epilogue: store UNNORMALIZED partial O + partial l into slot sg.
    // Slot layout: [64 rows][4 local heads][128 cols] bf16 (64 KB).
    const int sg = kvh * 80 + c;
    bf16_t* Op = (sg < 256) ? (OpD + (size_t)sg * 32768)
                            : (OpX + (size_t)(sg - 256) * 32768);
#pragma unroll
    for (int h = 0; h < 2; h++) {
        const int hl = (wave >> 2) * 2 + h;    // kvh-local head 0..3
        float lr = lsum[h];
        lr += __shfl_xor(lr, 16, 64);
        lr += __shfl_xor(lr, 32, 64);   // lane L: l for row offset L&15
        if (quad == 0)
            lpart[(size_t)sg * 256 + (rowg * 16 + l16) * 4 + hl] = lr;
#pragma unroll
        for (int r = 0; r < 4; r++) {
            int rr = rowg * 16 + quad * 4 + r;   // row within tile
#pragma unroll
            for (int dt = 0; dt < 8; dt++)
                Op[((size_t)rr * 4 + hl) * 128 + dt * 16 + l16] =
                    (bf16_t)(oacc[h][dt][r]);
        }
    }
}

// ---------------------------------------------------------------------------
// Combine: oh[s,h,:] = (sum_ci O_ci) / (sum_ci l_ci), ci over the 1..4
// chunk slots of q-tile qt = s>>6. 8 cols/thread.
// ---------------------------------------------------------------------------
__global__ __launch_bounds__(256) void flash_combine9(
    const bf16_t* __restrict__ OpD, const bf16_t* __restrict__ OpX,
    const float* __restrict__ lpart, bf16_t* __restrict__ oh)
{
    int i = (blockIdx.x * 256 + threadIdx.x) * 8;
    int s = i >> 11;            // row (2048 cols)
    int h = (i >> 7) & 15;      // head
    int col = i & 127;
    int qt = s >> 6;
    int f = qt >> 3;
    int base = qt + 4 * f * (f - 1) + (qt & 7) * f;   // sum_{j<qt} splits(j)
    int splits = 1 + f;
    int s0 = (h >> 2) * 80 + base;
    int roff = (s & 63) * 4 + (h & 3);
    float acc[8] = {0.f, 0.f, 0.f, 0.f, 0.f, 0.f, 0.f, 0.f};
    float l = 0.f;
    for (int ci = 0; ci < splits; ci++) {
        int sg = s0 + ci;
        const bf16_t* P = (sg < 256) ? (OpD + (size_t)sg * 32768)
                                     : (OpX + (size_t)(sg - 256) * 32768);
        bf16x8 a = *(const bf16x8*)&P[(size_t)roff * 128 + col];
#pragma unroll
        for (int j = 0; j < 8; j++) acc[j] += (float)a[j];
        l += lpart[(size_t)sg * 256 + roff];
    }
    float inv = 1.0f / l;
    bf16x8 o;
#pragma unroll
    for (int j = 0; j < 8; j++)
        o[j] = (bf16_t)(acc[j] * inv);
    *(bf16x8*)&oh[i] = o;
}

// ---------------------------------------------------------------------------
extern "C" void kernel_launch(void* const* d_in, const int* in_sizes, int n_in,
                              void* d_out, int out_size, void* d_ws, size_t ws_size,
                              hipStream_t stream)
{
    const float* x    = (const float*)d_in[0];
    const float* cosb = (const float*)d_in[1];
    const float* sinb = (const float*)d_in[2];
    const float* wq   = (const float*)d_in[3];
    const float* wk   = (const float*)d_in[4];
    const float* wv   = (const float*)d_in[5];
    const float* wo   = (const float*)d_in[6];
    float* out = (float*)d_out;

    // Workspace (28.5 MB):
    char* ws = (char*)d_ws;
    bf16_t* wb = (bf16_t*)(ws);                              // 0..12 MB: [wq;wk;wv] bf16 (reused for wo)
    bf16_t* qh = (bf16_t*)(ws + (size_t)12 * 1024 * 1024);   // 12..20 MB: q / attn-out
    bf16_t* kh = (bf16_t*)(ws + (size_t)20 * 1024 * 1024);   // 20..22 MB: k
    bf16_t* vT = (bf16_t*)(ws + (size_t)22 * 1024 * 1024);   // 22..24 MB: v^T
    float*  lp = (float*) (ws + (size_t)24 * 1024 * 1024);   // 24..24.32 MB: partial l (320x256 f32)
    bf16_t* opx = (bf16_t*)(ws + (size_t)24 * 1024 * 1024 + 512 * 1024); // 24.5..28.5 MB: slots 256..319
    // d_out (16 MB) doubles as scratch: x bf16 (steps 1-3), then partial
    // slots 0..255 (steps 5-6).
    bf16_t* xb  = (bf16_t*)d_out;
    bf16_t* opd = (bf16_t*)d_out;

    const int NX = S_LEN * HID;   // 4 Mi

    // 1) x -> bf16 (into d_out scratch)
    cvt_f32_bf16<<<NX / (256 * 8), 256, 0, stream>>>(x, xb, NX);

    // 2) weights -> bf16
    cvt_w3<<<6 * 1024 * 1024 / (256 * 8), 256, 0, stream>>>(wq, wk, wv, wb);

    // 3) fused QKV GEMM (all-bf16, 128x64 tile), routed outputs. 768 blocks.
    gemm128x64<1, bf16_t><<<dim3(48, 16), 256, 0, stream>>>(xb, wb, qh, kh, vT, 3072, HID);

    // 4) RoPE on q + k
    rope_all<<<dim3(S_LEN, 5), 128, 0, stream>>>(qh, kh, cosb, sinb);

    // 5) flash attention v9: balanced chunks (<=8 tiles), 320 blocks,
    //    71 KB LDS -> 2 blocks/CU.
    flash_attn9<<<dim3(80, NKV), 512, 0, stream>>>(qh, kh, vT, opd, opx, lp, S_LEN);

    // 6) combine partial slots -> qh (attn output, normalized bf16)
    flash_combine9<<<NX / (256 * 8), 256, 0, stream>>>(opd, opx, lp, qh);

    // 7) wo -> bf16 (reuses wb)
    cvt_f32_bf16<<<NX / (256 * 8), 256, 0, stream>>>(wo, wb, NX);

    // 8) out = attn_out @ wo^T -> fp32 d_out (overwrites partials). 512 blocks.
    gemm128x64<0, float><<<dim3(32, 16), 256, 0, stream>>>(qh, wb, out, nullptr, nullptr, HID, HID);
}

// Round 3
// 228.035 us; speedup vs baseline: 1.5148x; 1.5148x over previous
//
#include <hip/hip_runtime.h>
#include <hip/hip_bf16.h>

// Shapes (fixed): B=1, S=2048, HID=2048, NH=16, NKV=4, HD=128
// Inputs: fp32. Output: fp32. Internal compute: bf16 MFMA, fp32 accumulate.
typedef __bf16 bf16_t;
typedef __attribute__((ext_vector_type(8))) __bf16 bf16x8;
typedef __attribute__((ext_vector_type(4))) __bf16 bf16x4;
typedef __attribute__((ext_vector_type(4))) float f32x4;

#define S_LEN 2048
#define HID 2048
#define NH 16
#define NKV 4
#define HD 128

__device__ __forceinline__ void gll16(const bf16_t* g, bf16_t* l) {
    __builtin_amdgcn_global_load_lds(
        (const __attribute__((address_space(1))) unsigned int*)g,
        (__attribute__((address_space(3))) unsigned int*)l, 16, 0, 0);
}

__device__ __forceinline__ bf16x8 cvt2x4(float4 a, float4 b) {
    bf16x8 o;
    o[0]=(bf16_t)a.x; o[1]=(bf16_t)a.y; o[2]=(bf16_t)a.z; o[3]=(bf16_t)a.w;
    o[4]=(bf16_t)b.x; o[5]=(bf16_t)b.y; o[6]=(bf16_t)b.z; o[7]=(bf16_t)b.w;
    return o;
}

// ---------------------------------------------------------------------------
__global__ __launch_bounds__(256) void cvt_f32_bf16(const float* __restrict__ in,
                                                    bf16_t* __restrict__ out, int n)
{
    int i = (blockIdx.x * 256 + threadIdx.x) * 8;
    if (i >= n) return;
    float4 a = *(const float4*)&in[i];
    float4 b = *(const float4*)&in[i + 4];
    *(bf16x8*)&out[i] = cvt2x4(a, b);
}

// Fused weight conversion: [wq | wk | wv] fp32 -> contiguous bf16 (3072 x 2048)
__global__ __launch_bounds__(256) void cvt_w3(const float* __restrict__ wq,
                                              const float* __restrict__ wk,
                                              const float* __restrict__ wv,
                                              bf16_t* __restrict__ out)
{
    int i = (blockIdx.x * 256 + threadIdx.x) * 8;
    const float* src; int off;
    if (i < 4 * 1024 * 1024)      { src = wq; off = i; }
    else if (i < 5 * 1024 * 1024) { src = wk; off = i - 4 * 1024 * 1024; }
    else                          { src = wv; off = i - 5 * 1024 * 1024; }
    float4 a = *(const float4*)&src[off];
    float4 b = *(const float4*)&src[off + 4];
    *(bf16x8*)&out[i] = cvt2x4(a, b);
}

// ---------------------------------------------------------------------------
// m97-recipe NT GEMM, tile 128x64. QKV grid 48x16=768=3/CU, out grid
// 32x16=512=2/CU (both exactly divisible -> inter-block latency hiding).
// MODE 0: C fp32 row-major. MODE 1: qkv routing (C=q bf16 / Ck / Cvt^T).
// ---------------------------------------------------------------------------
template<int MODE, typename CT>
__global__ __launch_bounds__(256, 4) void gemm128x64(
    const bf16_t* __restrict__ A, const bf16_t* __restrict__ B,
    CT* __restrict__ C, bf16_t* __restrict__ CkP, bf16_t* __restrict__ CvtP,
    int N, int K)
{
    __shared__ __align__(16) bf16_t sA[128 * 64];   // 16 KB
    __shared__ __align__(16) bf16_t sB[64 * 64];    //  8 KB

    const int tid = threadIdx.x, lane = tid & 63, wave = tid >> 6;
    const int l16 = lane & 15, quad = lane >> 4;
    const int m0 = blockIdx.y * 128, n0 = blockIdx.x * 64;
    const int wm = (wave >> 1) * 64, wn = (wave & 1) * 32;

    const bf16_t* gA[4]; const bf16_t* gB[2];
    bf16_t* lA[4]; bf16_t* lB[2];
#pragma unroll
    for (int t = 0; t < 4; t++) {
        int p = (wave * 4 + t) * 64 + lane;
        int row = p >> 3;
        int lc = (p & 7) ^ (row & 7);
        gA[t] = A + (size_t)(m0 + row) * K + lc * 8;
        lA[t] = &sA[(wave * 4 + t) * 512];
    }
#pragma unroll
    for (int t = 0; t < 2; t++) {
        int p = (wave * 2 + t) * 64 + lane;
        int row = p >> 3;
        int lc = (p & 7) ^ (row & 7);
        gB[t] = B + (size_t)(n0 + row) * K + lc * 8;
        lB[t] = &sB[(wave * 2 + t) * 512];
    }

    int offA[2][4], offB[2][2];
#pragma unroll
    for (int kc = 0; kc < 2; kc++) {
#pragma unroll
        for (int i = 0; i < 4; i++) {
            int rm = wm + i * 16 + l16;
            offA[kc][i] = rm * 64 + (((kc * 4 + quad) ^ (rm & 7)) * 8);
        }
#pragma unroll
        for (int j = 0; j < 2; j++) {
            int rn = wn + j * 16 + l16;
            offB[kc][j] = rn * 64 + (((kc * 4 + quad) ^ (rn & 7)) * 8);
        }
    }

    f32x4 acc[4][2] = {};

    for (int k0 = 0; k0 < K; k0 += 64) {
        __syncthreads();
#pragma unroll
        for (int t = 0; t < 4; t++) { gll16(gA[t], lA[t]); gA[t] += 64; }
#pragma unroll
        for (int t = 0; t < 2; t++) { gll16(gB[t], lB[t]); gB[t] += 64; }
        __syncthreads();

#pragma unroll
        for (int kc = 0; kc < 2; kc++) {
            bf16x8 af[4], bfv[2];
#pragma unroll
            for (int i = 0; i < 4; i++) af[i] = *(bf16x8*)&sA[offA[kc][i]];
#pragma unroll
            for (int j = 0; j < 2; j++) bfv[j] = *(bf16x8*)&sB[offB[kc][j]];
#pragma unroll
            for (int i = 0; i < 4; i++)
#pragma unroll
                for (int j = 0; j < 2; j++)
                    acc[i][j] = __builtin_amdgcn_mfma_f32_16x16x32_bf16(af[i], bfv[j], acc[i][j], 0, 0, 0);
        }
    }

#pragma unroll
    for (int i = 0; i < 4; i++) {
        int rowb = m0 + wm + i * 16 + quad * 4;
#pragma unroll
        for (int j = 0; j < 2; j++) {
            int col = n0 + wn + j * 16 + l16;
#pragma unroll
            for (int r = 0; r < 4; r++) {
                float v = acc[i][j][r];
                int row = rowb + r;
                if (MODE == 0) {
                    C[(size_t)row * N + col] = (CT)v;
                } else {
                    if (col < 2048)      C[(size_t)row * 2048 + col] = (CT)v;
                    else if (col < 2560) CkP[(size_t)row * 512 + (col - 2048)] = (bf16_t)v;
                    else                 CvtP[(size_t)(col - 2560) * S_LEN + row] = (bf16_t)v;
                }
            }
        }
    }
}

// ---------------------------------------------------------------------------
// Fused RoPE over q (16 heads) and k (4 heads): grid (S, 5), block 128.
// ---------------------------------------------------------------------------
__global__ void rope_all(bf16_t* __restrict__ Qh, bf16_t* __restrict__ Kh,
                         const float* __restrict__ cosb, const float* __restrict__ sinb)
{
    int s = blockIdx.x;
    int grp = blockIdx.y;
    int sub = threadIdx.x >> 5;
    int i = threadIdx.x & 31;
    bf16_t* row = (grp < 4) ? (Qh + ((size_t)s * NH + grp * 4 + sub) * HD)
                            : (Kh + ((size_t)s * NKV + sub) * HD);
    float x0 = (float)row[2 * i];
    float x1 = (float)row[2 * i + 1];
    float p0 = (float)row[64 + 2 * i];
    float p1 = (float)row[64 + 2 * i + 1];
    float c0 = cosb[s * HD + 2 * i];
    float c1 = cosb[s * HD + 2 * i + 1];
    float n0 = sinb[s * HD + 2 * i];
    float n1 = sinb[s * HD + 2 * i + 1];
    float r0 = -x1, r1 = x0;
    row[2 * i]          = (bf16_t)(r0 * c0 + p0 * n0);
    row[2 * i + 1]      = (bf16_t)(r1 * c1 + p1 * n1);
    row[64 + 2 * i]     = (bf16_t)(-r0 * n0 + p0 * c0);
    row[64 + 2 * i + 1] = (bf16_t)(-r1 * n1 + p1 * c1);
}

// ---------------------------------------------------------------------------
// Flash attention v9b. v9 structure (balanced chunks + 71 KB LDS), but
// __launch_bounds__(512, 2) instead of (512, 4): the 4-waves/SIMD demand
// forced VGPRs 112->64 and SPILLED oacc to scratch (FETCH 19->203 MB,
// WRITE 17->259 MB, 13x HBM traffic -- the v9 regression). With the
// relaxed bound the natural ~112-VGPR allocation + 71 KB LDS gives
// 2 blocks/CU (4 waves/SIMD) at runtime without spill.
//  1. Balanced k-chunks: splits(qt)=1+qt/8, every chunk <= 8 tiles.
//     Grid (80 chunks, 4 kvh) = 320 blocks; partial slot per chunk.
//  2. LDS 71 KB: K single-buffered, V double-buffered. Per iter:
//     QK -> barrier A -> stage next K+V (overlaps exp/PV) -> barrier B.
//  3. s_setprio(1) around MFMA clusters (T5).
// Wave dataflow (16 q-rows x 2 heads, swapped QK, wave-private sP,
// unnormalized partials) unchanged from the verified v8.
// ---------------------------------------------------------------------------
__global__ __launch_bounds__(512, 2) void flash_attn9(
    const bf16_t* __restrict__ Q,   // S x (NH*HD)
    const bf16_t* __restrict__ Kb,  // S x (NKV*HD)
    const bf16_t* __restrict__ VT,  // (NKV*HD) x S
    bf16_t* __restrict__ OpD,       // partial slots 0..255 (d_out, 64KB each)
    bf16_t* __restrict__ OpX,       // partial slots 256..319 (ws)
    float* __restrict__ lpart,      // 320 x 256 fp32
    int S)
{
    __shared__ __align__(16) bf16_t sK[64 * 136];      // 17.4 KB (single buf)
    __shared__ __align__(16) bf16_t sVT[2][128 * 72];  // 36.9 KB (dbuf)
    __shared__ __align__(16) bf16_t sP[8][16 * 72];    // 18.4 KB, wave-private

    const int c   = blockIdx.x;          // chunk id 0..79
    const int kvh = blockIdx.y;
    // decode chunk -> (qt, ci): splits(qt) = 1 + qt/8
    int qt = 0, cb = 0;
    while (cb + 1 + (qt >> 3) <= c) { cb += 1 + (qt >> 3); qt++; }
    const int ci     = c - cb;
    const int splits = 1 + (qt >> 3);
    const int ntiles = qt + 1;
    const int tb = (ci * ntiles) / splits;
    const int te = ((ci + 1) * ntiles) / splits;

    const int q0  = qt * 64;
    const int tid = threadIdx.x, lane = tid & 63, wave = tid >> 6;
    const int l16 = lane & 15, quad = lane >> 4;
    const int rowg = wave & 3;                    // q-row group
    const int h0   = kvh * 4 + (wave >> 2) * 2;   // this wave's 2 heads
    const float scale = 0.08838834764831845f;     // 1/sqrt(128)

    const int qrow = q0 + rowg * 16 + l16;

    // Q fragments: 2 heads (B-operand of swapped QK)
    bf16x8 qf[2][4];
#pragma unroll
    for (int h = 0; h < 2; h++)
#pragma unroll
        for (int cc = 0; cc < 4; cc++)
            qf[h][cc] = *(const bf16x8*)&Q[(size_t)qrow * HID + (h0 + h) * HD + cc * 32 + quad * 8];

    f32x4 oacc[2][8] = {};
    float lsum[2] = {0.f, 0.f};

    // staging: 1024 16B-chunks per tile, 512 threads -> 2 chunks each
    int krow[2], kcol[2], vrow[2], vcol[2];
#pragma unroll
    for (int it = 0; it < 2; it++) {
        int cc = tid + 512 * it;
        krow[it] = cc >> 4; kcol[it] = (cc & 15) * 8;
        vrow[it] = cc >> 3; vcol[it] = (cc & 7) * 8;
    }

    // prologue: tile tb -> regs -> sK / sVT[0]; prefetch tb+1 into regs
    bf16x8 kpre[2], vpre[2];
#pragma unroll
    for (int it = 0; it < 2; it++) {
        kpre[it] = *(const bf16x8*)&Kb[(size_t)(tb * 64 + krow[it]) * (NKV * HD) + kvh * HD + kcol[it]];
        vpre[it] = *(const bf16x8*)&VT[((size_t)kvh * HD + vrow[it]) * S + tb * 64 + vcol[it]];
    }
#pragma unroll
    for (int it = 0; it < 2; it++) {
        *(bf16x8*)&sK[krow[it] * 136 + kcol[it]] = kpre[it];
        *(bf16x8*)&sVT[0][vrow[it] * 72 + vcol[it]] = vpre[it];
    }
    if (tb + 1 < te) {
        const int t1 = (tb + 1) * 64;
#pragma unroll
        for (int it = 0; it < 2; it++) {
            kpre[it] = *(const bf16x8*)&Kb[(size_t)(t1 + krow[it]) * (NKV * HD) + kvh * HD + kcol[it]];
            vpre[it] = *(const bf16x8*)&VT[((size_t)kvh * HD + vrow[it]) * S + t1 + vcol[it]];
        }
    }
    __syncthreads();

    int sel = 0;
    for (int kt = tb; kt < te; kt++) {
        const int t0 = kt * 64;
        const int ns = sel ^ 1;

        // ---- QK^T (swapped): nt outer, kf read once, 2 heads share it ----
        f32x4 sc[2][4];   // [h][nt]
        __builtin_amdgcn_s_setprio(1);
#pragma unroll
        for (int nt = 0; nt < 4; nt++) {
            bf16x8 kf[4];
#pragma unroll
            for (int cc = 0; cc < 4; cc++)
                kf[cc] = *(bf16x8*)&sK[(nt * 16 + l16) * 136 + cc * 32 + quad * 8];
#pragma unroll
            for (int h = 0; h < 2; h++) {
                f32x4 d = {};
#pragma unroll
                for (int cc = 0; cc < 4; cc++)
                    d = __builtin_amdgcn_mfma_f32_16x16x32_bf16(kf[cc], qf[h][cc], d, 0, 0, 0);
                sc[h][nt] = d;
            }
        }
        __builtin_amdgcn_s_setprio(0);

        __syncthreads();   // A: all waves done reading sK (tile kt)

        // stage tile kt+1: K into sK (freed above), V into sVT[ns].
        // These ds_writes overlap the exp + PV work below.
        if (kt + 1 < te) {
#pragma unroll
            for (int it = 0; it < 2; it++) {
                *(bf16x8*)&sK[krow[it] * 136 + kcol[it]] = kpre[it];
                *(bf16x8*)&sVT[ns][vrow[it] * 72 + vcol[it]] = vpre[it];
            }
            if (kt + 2 < te) {
                const int t2 = t0 + 128;
#pragma unroll
                for (int it = 0; it < 2; it++) {
                    kpre[it] = *(const bf16x8*)&Kb[(size_t)(t2 + krow[it]) * (NKV * HD) + kvh * HD + kcol[it]];
                    vpre[it] = *(const bf16x8*)&VT[((size_t)kvh * HD + vrow[it]) * S + t2 + vcol[it]];
                }
            }
        }

        // ---- exp + packed P write + A-frag read (wave-private sP) ----
        bf16x8 pa[2][2];
        if (kt == qt) {
#pragma unroll
            for (int h = 0; h < 2; h++) {
#pragma unroll
                for (int nt = 0; nt < 4; nt++) {
                    const int tbk = t0 + nt * 16 + quad * 4;
                    bf16x4 pk;
#pragma unroll
                    for (int r = 0; r < 4; r++) {
                        float p = (tbk + r <= qrow) ? __expf(sc[h][nt][r] * scale) : 0.0f;
                        lsum[h] += p;
                        pk[r] = (bf16_t)p;
                    }
                    *(bf16x4*)&sP[wave][l16 * 72 + nt * 16 + quad * 4] = pk;
                }
#pragma unroll
                for (int kc = 0; kc < 2; kc++)
                    pa[h][kc] = *(bf16x8*)&sP[wave][l16 * 72 + kc * 32 + quad * 8];
            }
        } else {
#pragma unroll
            for (int h = 0; h < 2; h++) {
#pragma unroll
                for (int nt = 0; nt < 4; nt++) {
                    bf16x4 pk;
#pragma unroll
                    for (int r = 0; r < 4; r++) {
                        float p = __expf(sc[h][nt][r] * scale);
                        lsum[h] += p;
                        pk[r] = (bf16_t)p;
                    }
                    *(bf16x4*)&sP[wave][l16 * 72 + nt * 16 + quad * 4] = pk;
                }
#pragma unroll
                for (int kc = 0; kc < 2; kc++)
                    pa[h][kc] = *(bf16x8*)&sP[wave][l16 * 72 + kc * 32 + quad * 8];
            }
        }

        // ---- PV: dt outer, vf read once, 2 heads share it ----
        __builtin_amdgcn_s_setprio(1);
#pragma unroll
        for (int dt = 0; dt < 8; dt++)
#pragma unroll
            for (int kc = 0; kc < 2; kc++) {
                bf16x8 vf = *(bf16x8*)&sVT[sel][(dt * 16 + l16) * 72 + kc * 32 + quad * 8];
#pragma unroll
                for (int h = 0; h < 2; h++)
                    oacc[h][dt] = __builtin_amdgcn_mfma_f32_16x16x32_bf16(pa[h][kc], vf, oacc[h][dt], 0, 0, 0);
            }
        __builtin_amdgcn_s_setprio(0);

        __syncthreads();   // B: sK/sVT[ns] writes visible; sVT[sel] reads done
        sel = ns;
    }

    // epilogue: store UNNORMALIZED partial O + partial l into slot sg.
    // Slot layout: [64 rows][4 local heads][128 cols] bf16 (64 KB).
    const int sg = kvh * 80 + c;
    bf16_t* Op = (sg < 256) ? (OpD + (size_t)sg * 32768)
                            : (OpX + (size_t)(sg - 256) * 32768);
#pragma unroll
    for (int h = 0; h < 2; h++) {
        const int hl = (wave >> 2) * 2 + h;    // kvh-local head 0..3
        float lr = lsum[h];
        lr += __shfl_xor(lr, 16, 64);
        lr += __shfl_xor(lr, 32, 64);   // lane L: l for row offset L&15
        if (quad == 0)
            lpart[(size_t)sg * 256 + (rowg * 16 + l16) * 4 + hl] = lr;
#pragma unroll
        for (int r = 0; r < 4; r++) {
            int rr = rowg * 16 + quad * 4 + r;   // row within tile
#pragma unroll
            for (int dt = 0; dt < 8; dt++)
                Op[((size_t)rr * 4 + hl) * 128 + dt * 16 + l16] =
                    (bf16_t)(oacc[h][dt][r]);
        }
    }
}

// ---------------------------------------------------------------------------
// Combine: oh[s,h,:] = (sum_ci O_ci) / (sum_ci l_ci), ci over the 1..4
// chunk slots of q-tile qt = s>>6. 8 cols/thread.
// ---------------------------------------------------------------------------
__global__ __launch_bounds__(256) void flash_combine9(
    const bf16_t* __restrict__ OpD, const bf16_t* __restrict__ OpX,
    const float* __restrict__ lpart, bf16_t* __restrict__ oh)
{
    int i = (blockIdx.x * 256 + threadIdx.x) * 8;
    int s = i >> 11;            // row (2048 cols)
    int h = (i >> 7) & 15;      // head
    int col = i & 127;
    int qt = s >> 6;
    int f = qt >> 3;
    int base = qt + 4 * f * (f - 1) + (qt & 7) * f;   // sum_{j<qt} splits(j)
    int splits = 1 + f;
    int s0 = (h >> 2) * 80 + base;
    int roff = (s & 63) * 4 + (h & 3);
    float acc[8] = {0.f, 0.f, 0.f, 0.f, 0.f, 0.f, 0.f, 0.f};
    float l = 0.f;
    for (int ci = 0; ci < splits; ci++) {
        int sg = s0 + ci;
        const bf16_t* P = (sg < 256) ? (OpD + (size_t)sg * 32768)
                                     : (OpX + (size_t)(sg - 256) * 32768);
        bf16x8 a = *(const bf16x8*)&P[(size_t)roff * 128 + col];
#pragma unroll
        for (int j = 0; j < 8; j++) acc[j] += (float)a[j];
        l += lpart[(size_t)sg * 256 + roff];
    }
    float inv = 1.0f / l;
    bf16x8 o;
#pragma unroll
    for (int j = 0; j < 8; j++)
        o[j] = (bf16_t)(acc[j] * inv);
    *(bf16x8*)&oh[i] = o;
}

// ---------------------------------------------------------------------------
extern "C" void kernel_launch(void* const* d_in, const int* in_sizes, int n_in,
                              void* d_out, int out_size, void* d_ws, size_t ws_size,
                              hipStream_t stream)
{
    const float* x    = (const float*)d_in[0];
    const float* cosb = (const float*)d_in[1];
    const float* sinb = (const float*)d_in[2];
    const float* wq   = (const float*)d_in[3];
    const float* wk   = (const float*)d_in[4];
    const float* wv   = (const float*)d_in[5];
    const float* wo   = (const float*)d_in[6];
    float* out = (float*)d_out;

    // Workspace (28.5 MB):
    char* ws = (char*)d_ws;
    bf16_t* wb = (bf16_t*)(ws);                              // 0..12 MB: [wq;wk;wv] bf16 (reused for wo)
    bf16_t* qh = (bf16_t*)(ws + (size_t)12 * 1024 * 1024);   // 12..20 MB: q / attn-out
    bf16_t* kh = (bf16_t*)(ws + (size_t)20 * 1024 * 1024);   // 20..22 MB: k
    bf16_t* vT = (bf16_t*)(ws + (size_t)22 * 1024 * 1024);   // 22..24 MB: v^T
    float*  lp = (float*) (ws + (size_t)24 * 1024 * 1024);   // 24..24.32 MB: partial l (320x256 f32)
    bf16_t* opx = (bf16_t*)(ws + (size_t)24 * 1024 * 1024 + 512 * 1024); // 24.5..28.5 MB: slots 256..319
    // d_out (16 MB) doubles as scratch: x bf16 (steps 1-3), then partial
    // slots 0..255 (steps 5-6).
    bf16_t* xb  = (bf16_t*)d_out;
    bf16_t* opd = (bf16_t*)d_out;

    const int NX = S_LEN * HID;   // 4 Mi

    // 1) x -> bf16 (into d_out scratch)
    cvt_f32_bf16<<<NX / (256 * 8), 256, 0, stream>>>(x, xb, NX);

    // 2) weights -> bf16
    cvt_w3<<<6 * 1024 * 1024 / (256 * 8), 256, 0, stream>>>(wq, wk, wv, wb);

    // 3) fused QKV GEMM (all-bf16, 128x64 tile), routed outputs. 768 blocks.
    gemm128x64<1, bf16_t><<<dim3(48, 16), 256, 0, stream>>>(xb, wb, qh, kh, vT, 3072, HID);

    // 4) RoPE on q + k
    rope_all<<<dim3(S_LEN, 5), 128, 0, stream>>>(qh, kh, cosb, sinb);

    // 5) flash attention v9b: balanced chunks (<=8 tiles), 320 blocks,
    //    71 KB LDS, natural VGPR (no spill) -> 2 blocks/CU.
    flash_attn9<<<dim3(80, NKV), 512, 0, stream>>>(qh, kh, vT, opd, opx, lp, S_LEN);

    // 6) combine partial slots -> qh (attn output, normalized bf16)
    flash_combine9<<<NX / (256 * 8), 256, 0, stream>>>(opd, opx, lp, qh);

    // 7) wo -> bf16 (reuses wb)
    cvt_f32_bf16<<<NX / (256 * 8), 256, 0, stream>>>(wo, wb, NX);

    // 8) out = attn_out @ wo^T -> fp32 d_out (overwrites partials). 512 blocks.
    gemm128x64<0, float><<<dim3(32, 16), 256, 0, stream>>>(qh, wb, out, nullptr, nullptr, HID, HID);
}

// Round 4
// 214.638 us; speedup vs baseline: 1.6093x; 1.0624x over previous
//
#include <hip/hip_runtime.h>
#include <hip/hip_bf16.h>

// Shapes (fixed): B=1, S=2048, HID=2048, NH=16, NKV=4, HD=128
// Inputs: fp32. Output: fp32. Internal compute: bf16 MFMA, fp32 accumulate.
typedef __bf16 bf16_t;
typedef __attribute__((ext_vector_type(8))) __bf16 bf16x8;
typedef __attribute__((ext_vector_type(4))) __bf16 bf16x4;
typedef __attribute__((ext_vector_type(4))) float f32x4;

#define S_LEN 2048
#define HID 2048
#define NH 16
#define NKV 4
#define HD 128

__device__ __forceinline__ void gll16(const bf16_t* g, bf16_t* l) {
    __builtin_amdgcn_global_load_lds(
        (const __attribute__((address_space(1))) unsigned int*)g,
        (__attribute__((address_space(3))) unsigned int*)l, 16, 0, 0);
}

__device__ __forceinline__ bf16x8 cvt2x4(float4 a, float4 b) {
    bf16x8 o;
    o[0]=(bf16_t)a.x; o[1]=(bf16_t)a.y; o[2]=(bf16_t)a.z; o[3]=(bf16_t)a.w;
    o[4]=(bf16_t)b.x; o[5]=(bf16_t)b.y; o[6]=(bf16_t)b.z; o[7]=(bf16_t)b.w;
    return o;
}

// ---------------------------------------------------------------------------
__global__ __launch_bounds__(256) void cvt_f32_bf16(const float* __restrict__ in,
                                                    bf16_t* __restrict__ out, int n)
{
    int i = (blockIdx.x * 256 + threadIdx.x) * 8;
    if (i >= n) return;
    float4 a = *(const float4*)&in[i];
    float4 b = *(const float4*)&in[i + 4];
    *(bf16x8*)&out[i] = cvt2x4(a, b);
}

// Fused weight conversion: [wq | wk | wv] fp32 -> contiguous bf16 (3072 x 2048)
__global__ __launch_bounds__(256) void cvt_w3(const float* __restrict__ wq,
                                              const float* __restrict__ wk,
                                              const float* __restrict__ wv,
                                              bf16_t* __restrict__ out)
{
    int i = (blockIdx.x * 256 + threadIdx.x) * 8;
    const float* src; int off;
    if (i < 4 * 1024 * 1024)      { src = wq; off = i; }
    else if (i < 5 * 1024 * 1024) { src = wk; off = i - 4 * 1024 * 1024; }
    else                          { src = wv; off = i - 5 * 1024 * 1024; }
    float4 a = *(const float4*)&src[off];
    float4 b = *(const float4*)&src[off + 4];
    *(bf16x8*)&out[i] = cvt2x4(a, b);
}

// ---------------------------------------------------------------------------
// m97-recipe NT GEMM, tile 128x64. QKV grid 48x16=768=3/CU, out grid
// 32x16=512=2/CU (both exactly divisible -> inter-block latency hiding).
// MODE 0: C fp32 row-major. MODE 1: qkv routing (C=q bf16 / Ck / Cvt^T).
// ---------------------------------------------------------------------------
template<int MODE, typename CT>
__global__ __launch_bounds__(256, 4) void gemm128x64(
    const bf16_t* __restrict__ A, const bf16_t* __restrict__ B,
    CT* __restrict__ C, bf16_t* __restrict__ CkP, bf16_t* __restrict__ CvtP,
    int N, int K)
{
    __shared__ __align__(16) bf16_t sA[128 * 64];   // 16 KB
    __shared__ __align__(16) bf16_t sB[64 * 64];    //  8 KB

    const int tid = threadIdx.x, lane = tid & 63, wave = tid >> 6;
    const int l16 = lane & 15, quad = lane >> 4;
    const int m0 = blockIdx.y * 128, n0 = blockIdx.x * 64;
    const int wm = (wave >> 1) * 64, wn = (wave & 1) * 32;

    const bf16_t* gA[4]; const bf16_t* gB[2];
    bf16_t* lA[4]; bf16_t* lB[2];
#pragma unroll
    for (int t = 0; t < 4; t++) {
        int p = (wave * 4 + t) * 64 + lane;
        int row = p >> 3;
        int lc = (p & 7) ^ (row & 7);
        gA[t] = A + (size_t)(m0 + row) * K + lc * 8;
        lA[t] = &sA[(wave * 4 + t) * 512];
    }
#pragma unroll
    for (int t = 0; t < 2; t++) {
        int p = (wave * 2 + t) * 64 + lane;
        int row = p >> 3;
        int lc = (p & 7) ^ (row & 7);
        gB[t] = B + (size_t)(n0 + row) * K + lc * 8;
        lB[t] = &sB[(wave * 2 + t) * 512];
    }

    int offA[2][4], offB[2][2];
#pragma unroll
    for (int kc = 0; kc < 2; kc++) {
#pragma unroll
        for (int i = 0; i < 4; i++) {
            int rm = wm + i * 16 + l16;
            offA[kc][i] = rm * 64 + (((kc * 4 + quad) ^ (rm & 7)) * 8);
        }
#pragma unroll
        for (int j = 0; j < 2; j++) {
            int rn = wn + j * 16 + l16;
            offB[kc][j] = rn * 64 + (((kc * 4 + quad) ^ (rn & 7)) * 8);
        }
    }

    f32x4 acc[4][2] = {};

    for (int k0 = 0; k0 < K; k0 += 64) {
        __syncthreads();
#pragma unroll
        for (int t = 0; t < 4; t++) { gll16(gA[t], lA[t]); gA[t] += 64; }
#pragma unroll
        for (int t = 0; t < 2; t++) { gll16(gB[t], lB[t]); gB[t] += 64; }
        __syncthreads();

#pragma unroll
        for (int kc = 0; kc < 2; kc++) {
            bf16x8 af[4], bfv[2];
#pragma unroll
            for (int i = 0; i < 4; i++) af[i] = *(bf16x8*)&sA[offA[kc][i]];
#pragma unroll
            for (int j = 0; j < 2; j++) bfv[j] = *(bf16x8*)&sB[offB[kc][j]];
#pragma unroll
            for (int i = 0; i < 4; i++)
#pragma unroll
                for (int j = 0; j < 2; j++)
                    acc[i][j] = __builtin_amdgcn_mfma_f32_16x16x32_bf16(af[i], bfv[j], acc[i][j], 0, 0, 0);
        }
    }

#pragma unroll
    for (int i = 0; i < 4; i++) {
        int rowb = m0 + wm + i * 16 + quad * 4;
#pragma unroll
        for (int j = 0; j < 2; j++) {
            int col = n0 + wn + j * 16 + l16;
#pragma unroll
            for (int r = 0; r < 4; r++) {
                float v = acc[i][j][r];
                int row = rowb + r;
                if (MODE == 0) {
                    C[(size_t)row * N + col] = (CT)v;
                } else {
                    if (col < 2048)      C[(size_t)row * 2048 + col] = (CT)v;
                    else if (col < 2560) CkP[(size_t)row * 512 + (col - 2048)] = (bf16_t)v;
                    else                 CvtP[(size_t)(col - 2560) * S_LEN + row] = (bf16_t)v;
                }
            }
        }
    }
}

// ---------------------------------------------------------------------------
// Fused RoPE over q (16 heads) and k (4 heads): grid (S, 5), block 128.
// ---------------------------------------------------------------------------
__global__ void rope_all(bf16_t* __restrict__ Qh, bf16_t* __restrict__ Kh,
                         const float* __restrict__ cosb, const float* __restrict__ sinb)
{
    int s = blockIdx.x;
    int grp = blockIdx.y;
    int sub = threadIdx.x >> 5;
    int i = threadIdx.x & 31;
    bf16_t* row = (grp < 4) ? (Qh + ((size_t)s * NH + grp * 4 + sub) * HD)
                            : (Kh + ((size_t)s * NKV + sub) * HD);
    float x0 = (float)row[2 * i];
    float x1 = (float)row[2 * i + 1];
    float p0 = (float)row[64 + 2 * i];
    float p1 = (float)row[64 + 2 * i + 1];
    float c0 = cosb[s * HD + 2 * i];
    float c1 = cosb[s * HD + 2 * i + 1];
    float n0 = sinb[s * HD + 2 * i];
    float n1 = sinb[s * HD + 2 * i + 1];
    float r0 = -x1, r1 = x0;
    row[2 * i]          = (bf16_t)(r0 * c0 + p0 * n0);
    row[2 * i + 1]      = (bf16_t)(r1 * c1 + p1 * n1);
    row[64 + 2 * i]     = (bf16_t)(-r0 * n0 + p0 * c0);
    row[64 + 2 * i + 1] = (bf16_t)(-r1 * n1 + p1 * c1);
}

// ---------------------------------------------------------------------------
// Flash attention v10: PERFECT per-CU balance via triangle pairing.
// Counters show the kernel is LDS-throughput-bound per CU (~4.9k LDS-pipe
// cycles per tile-iter vs 640 MFMA cycles/SIMD -> MfmaUtil ceiling ~15%,
// measured 13.5%); co-residency can't help a saturated shared pipe, only
// per-CU work reduction can. v9's 320-block grid left 64 CUs with 2 chunks
// (16 units) while 192 CUs ran ~6.6 -> makespan ~= v8.
// Pairing: q-tile p with 31-p gives exactly 33 tile-units per pair; split
// into 4 chunks of 9/8/8/8 -> 64 chunks/kvh, grid (64,4) = 256 blocks =
// 1 block/CU, every CU <= 9 units. A chunk straddling the pair boundary
// flushes its partial mid-chunk (second slot 64+p).
// 1 block/CU by construction -> restore v8 full dbuf (K+V, 90 KB LDS,
// ONE barrier/iter). Wave dataflow unchanged (verified v8).
// ---------------------------------------------------------------------------
__global__ __launch_bounds__(512, 1) void flash_attn10(
    const bf16_t* __restrict__ Q,   // S x (NH*HD)
    const bf16_t* __restrict__ Kb,  // S x (NKV*HD)
    const bf16_t* __restrict__ VT,  // (NKV*HD) x S
    bf16_t* __restrict__ OpD,       // partial slots 0..255 (d_out, 64KB each)
    bf16_t* __restrict__ OpX,       // partial slots 256..319 (ws)
    float* __restrict__ lpart,      // 320 x 256 fp32
    int S)
{
    __shared__ __align__(16) bf16_t sK[2][64 * 136];   // 34.8 KB (dbuf)
    __shared__ __align__(16) bf16_t sVT[2][128 * 72];  // 36.9 KB (dbuf)
    __shared__ __align__(16) bf16_t sP[8][16 * 72];    // 18.4 KB, wave-private

    const int c   = blockIdx.x;          // chunk 0..63
    const int kvh = blockIdx.y;
    const int p   = c >> 2, sub = c & 3; // pair p: qtA=p, qtB=31-p
    const int ts   = (33 * sub + 3) >> 2;    // chunk t-range [ts, tend)
    const int tend = (33 * sub + 36) >> 2;   // sizes 9,8,8,8 over t=0..32
    const int tA   = p + 1;                  // t < tA -> qtA, else qtB

    const int tid = threadIdx.x, lane = tid & 63, wave = tid >> 6;
    const int l16 = lane & 15, quad = lane >> 4;
    const int rowg = wave & 3;                    // q-row group
    const int h0   = kvh * 4 + (wave >> 2) * 2;   // this wave's 2 heads
    const float scale = 0.08838834764831845f;     // 1/sqrt(128)

    // staging: 1024 16B-chunks per tile, 512 threads -> 2 chunks each
    int krow[2], kcol[2], vrow[2], vcol[2];
#pragma unroll
    for (int it = 0; it < 2; it++) {
        int cc = tid + 512 * it;
        krow[it] = cc >> 4; kcol[it] = (cc & 15) * 8;
        vrow[it] = cc >> 3; vcol[it] = (cc & 7) * 8;
    }

    // Up to 2 segments: first = A-part (or whole-B chunk), second = B-part
    // of a straddling chunk.
#pragma unroll
    for (int sI = 0; sI < 2; sI++) {
        int st0, st1, sqt, ssl;
        if (sI == 0) {
            if (ts < tA) { st0 = ts; st1 = (tend < tA ? tend : tA); sqt = p;      ssl = c; }
            else         { st0 = ts; st1 = tend;                    sqt = 31 - p; ssl = c; }
        } else {
            if (!(ts < tA && tend > tA)) break;
            st0 = tA; st1 = tend; sqt = 31 - p; ssl = 64 + p;
        }
        const int base = (sqt == p) ? 0 : tA;   // kt = t - base
        const int kb = st0 - base, ke = st1 - base;
        const int qt = sqt;
        const int q0 = qt * 64;
        const int qrow = q0 + rowg * 16 + l16;

        // Q fragments: 2 heads (B-operand of swapped QK)
        bf16x8 qf[2][4];
#pragma unroll
        for (int h = 0; h < 2; h++)
#pragma unroll
            for (int cc = 0; cc < 4; cc++)
                qf[h][cc] = *(const bf16x8*)&Q[(size_t)qrow * HID + (h0 + h) * HD + cc * 32 + quad * 8];

        f32x4 oacc[2][8] = {};
        float lsum[2] = {0.f, 0.f};

        // prologue: tile kb -> regs -> buf0; prefetch kb+1 into regs
        bf16x8 kpre[2], vpre[2];
#pragma unroll
        for (int it = 0; it < 2; it++) {
            kpre[it] = *(const bf16x8*)&Kb[(size_t)(kb * 64 + krow[it]) * (NKV * HD) + kvh * HD + kcol[it]];
            vpre[it] = *(const bf16x8*)&VT[((size_t)kvh * HD + vrow[it]) * S + kb * 64 + vcol[it]];
        }
#pragma unroll
        for (int it = 0; it < 2; it++) {
            *(bf16x8*)&sK[0][krow[it] * 136 + kcol[it]] = kpre[it];
            *(bf16x8*)&sVT[0][vrow[it] * 72 + vcol[it]] = vpre[it];
        }
        if (kb + 1 < ke) {
            const int t1 = (kb + 1) * 64;
#pragma unroll
            for (int it = 0; it < 2; it++) {
                kpre[it] = *(const bf16x8*)&Kb[(size_t)(t1 + krow[it]) * (NKV * HD) + kvh * HD + kcol[it]];
                vpre[it] = *(const bf16x8*)&VT[((size_t)kvh * HD + vrow[it]) * S + t1 + vcol[it]];
            }
        }
        __syncthreads();

        int sel = 0;
        for (int kt = kb; kt < ke; kt++) {
            const int t0 = kt * 64;
            const int ns = sel ^ 1;

            // stage tile kt+1 into the other buffers (overlaps compute)
            if (kt + 1 < ke) {
#pragma unroll
                for (int it = 0; it < 2; it++) {
                    *(bf16x8*)&sK[ns][krow[it] * 136 + kcol[it]] = kpre[it];
                    *(bf16x8*)&sVT[ns][vrow[it] * 72 + vcol[it]] = vpre[it];
                }
                if (kt + 2 < ke) {
                    const int t2 = t0 + 128;
#pragma unroll
                    for (int it = 0; it < 2; it++) {
                        kpre[it] = *(const bf16x8*)&Kb[(size_t)(t2 + krow[it]) * (NKV * HD) + kvh * HD + kcol[it]];
                        vpre[it] = *(const bf16x8*)&VT[((size_t)kvh * HD + vrow[it]) * S + t2 + vcol[it]];
                    }
                }
            }

            // ---- QK^T (swapped): nt outer, kf read once, 2 heads share ----
            f32x4 sc[2][4];   // [h][nt]
            __builtin_amdgcn_s_setprio(1);
#pragma unroll
            for (int nt = 0; nt < 4; nt++) {
                bf16x8 kf[4];
#pragma unroll
                for (int cc = 0; cc < 4; cc++)
                    kf[cc] = *(bf16x8*)&sK[sel][(nt * 16 + l16) * 136 + cc * 32 + quad * 8];
#pragma unroll
                for (int h = 0; h < 2; h++) {
                    f32x4 d = {};
#pragma unroll
                    for (int cc = 0; cc < 4; cc++)
                        d = __builtin_amdgcn_mfma_f32_16x16x32_bf16(kf[cc], qf[h][cc], d, 0, 0, 0);
                    sc[h][nt] = d;
                }
            }
            __builtin_amdgcn_s_setprio(0);

            // ---- exp + packed P write + A-frag read (wave-private sP) ----
            bf16x8 pa[2][2];
            if (kt == qt) {
#pragma unroll
                for (int h = 0; h < 2; h++) {
#pragma unroll
                    for (int nt = 0; nt < 4; nt++) {
                        const int tbk = t0 + nt * 16 + quad * 4;
                        bf16x4 pk;
#pragma unroll
                        for (int r = 0; r < 4; r++) {
                            float pv = (tbk + r <= qrow) ? __expf(sc[h][nt][r] * scale) : 0.0f;
                            lsum[h] += pv;
                            pk[r] = (bf16_t)pv;
                        }
                        *(bf16x4*)&sP[wave][l16 * 72 + nt * 16 + quad * 4] = pk;
                    }
#pragma unroll
                    for (int kc = 0; kc < 2; kc++)
                        pa[h][kc] = *(bf16x8*)&sP[wave][l16 * 72 + kc * 32 + quad * 8];
                }
            } else {
#pragma unroll
                for (int h = 0; h < 2; h++) {
#pragma unroll
                    for (int nt = 0; nt < 4; nt++) {
                        bf16x4 pk;
#pragma unroll
                        for (int r = 0; r < 4; r++) {
                            float pv = __expf(sc[h][nt][r] * scale);
                            lsum[h] += pv;
                            pk[r] = (bf16_t)pv;
                        }
                        *(bf16x4*)&sP[wave][l16 * 72 + nt * 16 + quad * 4] = pk;
                    }
#pragma unroll
                    for (int kc = 0; kc < 2; kc++)
                        pa[h][kc] = *(bf16x8*)&sP[wave][l16 * 72 + kc * 32 + quad * 8];
                }
            }

            // ---- PV: dt outer, vf read once, 2 heads share it ----
            __builtin_amdgcn_s_setprio(1);
#pragma unroll
            for (int dt = 0; dt < 8; dt++)
#pragma unroll
                for (int kc = 0; kc < 2; kc++) {
                    bf16x8 vf = *(bf16x8*)&sVT[sel][(dt * 16 + l16) * 72 + kc * 32 + quad * 8];
#pragma unroll
                    for (int h = 0; h < 2; h++)
                        oacc[h][dt] = __builtin_amdgcn_mfma_f32_16x16x32_bf16(pa[h][kc], vf, oacc[h][dt], 0, 0, 0);
                }
            __builtin_amdgcn_s_setprio(0);

            __syncthreads();   // buf[ns] writes visible; buf[sel] reads done
            sel = ns;
        }

        // epilogue: store UNNORMALIZED partial O + partial l into slot sg.
        // Slot layout: [64 rows][4 local heads][128 cols] bf16 (64 KB).
        const int sg = kvh * 80 + ssl;
        bf16_t* Op = (sg < 256) ? (OpD + (size_t)sg * 32768)
                                : (OpX + (size_t)(sg - 256) * 32768);
#pragma unroll
        for (int h = 0; h < 2; h++) {
            const int hl = (wave >> 2) * 2 + h;    // kvh-local head 0..3
            float lr = lsum[h];
            lr += __shfl_xor(lr, 16, 64);
            lr += __shfl_xor(lr, 32, 64);   // lane L: l for row offset L&15
            if (quad == 0)
                lpart[(size_t)sg * 256 + (rowg * 16 + l16) * 4 + hl] = lr;
#pragma unroll
            for (int r = 0; r < 4; r++) {
                int rr = rowg * 16 + quad * 4 + r;   // row within tile
#pragma unroll
                for (int dt = 0; dt < 8; dt++)
                    Op[((size_t)rr * 4 + hl) * 128 + dt * 16 + l16] =
                        (bf16_t)(oacc[h][dt][r]);
            }
        }
        // next segment (if any) restages buf0; all LDS reads of this segment
        // completed before the loop's final barrier.
    }
}

// ---------------------------------------------------------------------------
// Combine: oh[s,h,:] = (sum O_slot) / (sum l_slot) over the <=4 slots that
// contributed to q-tile qt = s>>6. Slot enumeration mirrors flash_attn10:
//  qt<=15 (A-side of pair p=qt): chunks with ts < qt+1, first-segment slot.
//  qt>=16 (B-side, p=31-qt): chunks with tend > p+1; straddler uses 64+p.
// ---------------------------------------------------------------------------
__global__ __launch_bounds__(256) void flash_combine10(
    const bf16_t* __restrict__ OpD, const bf16_t* __restrict__ OpX,
    const float* __restrict__ lpart, bf16_t* __restrict__ oh)
{
    int i = (blockIdx.x * 256 + threadIdx.x) * 8;
    int s = i >> 11;            // row (2048 cols)
    int h = (i >> 7) & 15;      // head
    int col = i & 127;
    int qt = s >> 6;
    int base80 = (h >> 2) * 80;
    int roff = (s & 63) * 4 + (h & 3);

    int sl[4]; int nsl = 0;
    if (qt <= 15) {
        int pr = qt;
#pragma unroll
        for (int sub = 0; sub < 4; sub++) {
            int tss = (33 * sub + 3) >> 2;
            if (tss < qt + 1) sl[nsl++] = pr * 4 + sub;
        }
    } else {
        int pr = 31 - qt, tAh = pr + 1;
#pragma unroll
        for (int sub = 0; sub < 4; sub++) {
            int tss = (33 * sub + 3) >> 2;
            int ten = (33 * sub + 36) >> 2;
            if (ten > tAh) sl[nsl++] = (tss < tAh) ? 64 + pr : pr * 4 + sub;
        }
    }

    float acc[8] = {0.f, 0.f, 0.f, 0.f, 0.f, 0.f, 0.f, 0.f};
    float l = 0.f;
    for (int ci = 0; ci < nsl; ci++) {
        int sg = base80 + sl[ci];
        const bf16_t* P = (sg < 256) ? (OpD + (size_t)sg * 32768)
                                     : (OpX + (size_t)(sg - 256) * 32768);
        bf16x8 a = *(const bf16x8*)&P[(size_t)roff * 128 + col];
#pragma unroll
        for (int j = 0; j < 8; j++) acc[j] += (float)a[j];
        l += lpart[(size_t)sg * 256 + roff];
    }
    float inv = 1.0f / l;
    bf16x8 o;
#pragma unroll
    for (int j = 0; j < 8; j++)
        o[j] = (bf16_t)(acc[j] * inv);
    *(bf16x8*)&oh[i] = o;
}

// ---------------------------------------------------------------------------
extern "C" void kernel_launch(void* const* d_in, const int* in_sizes, int n_in,
                              void* d_out, int out_size, void* d_ws, size_t ws_size,
                              hipStream_t stream)
{
    const float* x    = (const float*)d_in[0];
    const float* cosb = (const float*)d_in[1];
    const float* sinb = (const float*)d_in[2];
    const float* wq   = (const float*)d_in[3];
    const float* wk   = (const float*)d_in[4];
    const float* wv   = (const float*)d_in[5];
    const float* wo   = (const float*)d_in[6];
    float* out = (float*)d_out;

    // Workspace (28.5 MB):
    char* ws = (char*)d_ws;
    bf16_t* wb = (bf16_t*)(ws);                              // 0..12 MB: [wq;wk;wv] bf16 (reused for wo)
    bf16_t* qh = (bf16_t*)(ws + (size_t)12 * 1024 * 1024);   // 12..20 MB: q / attn-out
    bf16_t* kh = (bf16_t*)(ws + (size_t)20 * 1024 * 1024);   // 20..22 MB: k
    bf16_t* vT = (bf16_t*)(ws + (size_t)22 * 1024 * 1024);   // 22..24 MB: v^T
    float*  lp = (float*) (ws + (size_t)24 * 1024 * 1024);   // 24..24.32 MB: partial l (320x256 f32)
    bf16_t* opx = (bf16_t*)(ws + (size_t)24 * 1024 * 1024 + 512 * 1024); // 24.5..28.5 MB: slots 256..319
    // d_out (16 MB) doubles as scratch: x bf16 (steps 1-3), then partial
    // slots 0..255 (steps 5-6).
    bf16_t* xb  = (bf16_t*)d_out;
    bf16_t* opd = (bf16_t*)d_out;

    const int NX = S_LEN * HID;   // 4 Mi

    // 1) x -> bf16 (into d_out scratch)
    cvt_f32_bf16<<<NX / (256 * 8), 256, 0, stream>>>(x, xb, NX);

    // 2) weights -> bf16
    cvt_w3<<<6 * 1024 * 1024 / (256 * 8), 256, 0, stream>>>(wq, wk, wv, wb);

    // 3) fused QKV GEMM (all-bf16, 128x64 tile), routed outputs. 768 blocks.
    gemm128x64<1, bf16_t><<<dim3(48, 16), 256, 0, stream>>>(xb, wb, qh, kh, vT, 3072, HID);

    // 4) RoPE on q + k
    rope_all<<<dim3(S_LEN, 5), 128, 0, stream>>>(qh, kh, cosb, sinb);

    // 5) flash attention v10: paired-triangle chunks, 256 blocks = 1/CU,
    //    every CU <= 9 tile-units, 90 KB LDS full dbuf, 1 barrier/iter.
    flash_attn10<<<dim3(64, NKV), 512, 0, stream>>>(qh, kh, vT, opd, opx, lp, S_LEN);

    // 6) combine partial slots -> qh (attn output, normalized bf16)
    flash_combine10<<<NX / (256 * 8), 256, 0, stream>>>(opd, opx, lp, qh);

    // 7) wo -> bf16 (reuses wb)
    cvt_f32_bf16<<<NX / (256 * 8), 256, 0, stream>>>(wo, wb, NX);

    // 8) out = attn_out @ wo^T -> fp32 d_out (overwrites partials). 512 blocks.
    gemm128x64<0, float><<<dim3(32, 16), 256, 0, stream>>>(qh, wb, out, nullptr, nullptr, HID, HID);
}

// Round 6
// 212.932 us; speedup vs baseline: 1.6222x; 1.0080x over previous
//
#include <hip/hip_runtime.h>
#include <hip/hip_bf16.h>

// Shapes (fixed): B=1, S=2048, HID=2048, NH=16, NKV=4, HD=128
// Inputs: fp32. Output: fp32. Internal compute: bf16 MFMA, fp32 accumulate.
typedef __bf16 bf16_t;
typedef __attribute__((ext_vector_type(8))) __bf16 bf16x8;
typedef __attribute__((ext_vector_type(4))) __bf16 bf16x4;
typedef __attribute__((ext_vector_type(4))) float f32x4;

#define S_LEN 2048
#define HID 2048
#define NH 16
#define NKV 4
#define HD 128

__device__ __forceinline__ void gll16(const bf16_t* g, bf16_t* l) {
    __builtin_amdgcn_global_load_lds(
        (const __attribute__((address_space(1))) unsigned int*)g,
        (__attribute__((address_space(3))) unsigned int*)l, 16, 0, 0);
}

__device__ __forceinline__ bf16x8 cvt2x4(float4 a, float4 b) {
    bf16x8 o;
    o[0]=(bf16_t)a.x; o[1]=(bf16_t)a.y; o[2]=(bf16_t)a.z; o[3]=(bf16_t)a.w;
    o[4]=(bf16_t)b.x; o[5]=(bf16_t)b.y; o[6]=(bf16_t)b.z; o[7]=(bf16_t)b.w;
    return o;
}

// ---------------------------------------------------------------------------
// Fused conversion: x (4Mi) -> xb, [wq|wk|wv] (6Mi) -> wb. 10Mi elems,
// 8/thread, 5120 blocks. (wo is converted later, into the freed wb --
// keeps workspace within the proven 28.5 MB envelope.)
// ---------------------------------------------------------------------------
__global__ __launch_bounds__(256) void cvt_all(
    const float* __restrict__ x,  const float* __restrict__ wq,
    const float* __restrict__ wk, const float* __restrict__ wv,
    bf16_t* __restrict__ xb, bf16_t* __restrict__ wb)
{
    const size_t M = 1024 * 1024;
    size_t g = ((size_t)blockIdx.x * 256 + threadIdx.x) * 8;
    const float* src; bf16_t* dst; size_t soff, doff;
    if (g < 4 * M) {
        src = x; dst = xb; soff = g; doff = g;
    } else {
        size_t w = g - 4 * M; dst = wb; doff = w;
        if (w < 4 * M)      { src = wq; soff = w; }
        else if (w < 5 * M) { src = wk; soff = w - 4 * M; }
        else                { src = wv; soff = w - 5 * M; }
    }
    float4 a = *(const float4*)&src[soff];
    float4 b = *(const float4*)&src[soff + 4];
    *(bf16x8*)&dst[doff] = cvt2x4(a, b);
}

__global__ __launch_bounds__(256) void cvt_f32_bf16(const float* __restrict__ in,
                                                    bf16_t* __restrict__ out, int n)
{
    int i = (blockIdx.x * 256 + threadIdx.x) * 8;
    if (i >= n) return;
    float4 a = *(const float4*)&in[i];
    float4 b = *(const float4*)&in[i + 4];
    *(bf16x8*)&out[i] = cvt2x4(a, b);
}

// ---------------------------------------------------------------------------
// NT GEMM, tile 128x64, 2-PHASE DOUBLE-BUFFERED (T3-minimal): the old loop
// {barrier; issue gll16; barrier; compute} exposed the full L2/HBM latency
// of the staging batch every K-step. Now tile k+1 is staged into buf^1
// BEFORE computing buf (loads in flight under ds_read+MFMA); one
// __syncthreads per iter (its implicit vmcnt(0) drain lands on
// mostly-complete loads). LDS 48 KB: QKV grid 48x16=768 -> 3 blocks/CU
// (144 KB), out grid 32x16=512 -> 2/CU.
// MODE 0: C fp32 row-major. MODE 1: qkv routing (C=q bf16 / Ck / Cvt^T).
// ---------------------------------------------------------------------------
template<int MODE, typename CT>
__global__ __launch_bounds__(256, 4) void gemm128x64(
    const bf16_t* __restrict__ A, const bf16_t* __restrict__ B,
    CT* __restrict__ C, bf16_t* __restrict__ CkP, bf16_t* __restrict__ CvtP,
    int N, int K)
{
    __shared__ __align__(16) bf16_t sA[2][128 * 64];   // 32 KB
    __shared__ __align__(16) bf16_t sB[2][64 * 64];    // 16 KB

    const int tid = threadIdx.x, lane = tid & 63, wave = tid >> 6;
    const int l16 = lane & 15, quad = lane >> 4;
    const int m0 = blockIdx.y * 128, n0 = blockIdx.x * 64;
    const int wm = (wave >> 1) * 64, wn = (wave & 1) * 32;

    // gll16 LDS dest is the wave-uniform base (hardware adds lane*16B).
    const bf16_t* gA[4]; const bf16_t* gB[2];
    int laOff[4], lbOff[2];
#pragma unroll
    for (int t = 0; t < 4; t++) {
        int p = (wave * 4 + t) * 64 + lane;
        int row = p >> 3;
        int lc = (p & 7) ^ (row & 7);
        gA[t] = A + (size_t)(m0 + row) * K + lc * 8;
        laOff[t] = (wave * 4 + t) * 512;
    }
#pragma unroll
    for (int t = 0; t < 2; t++) {
        int p = (wave * 2 + t) * 64 + lane;
        int row = p >> 3;
        int lc = (p & 7) ^ (row & 7);
        gB[t] = B + (size_t)(n0 + row) * K + lc * 8;
        lbOff[t] = (wave * 2 + t) * 512;
    }

    int offA[2][4], offB[2][2];
#pragma unroll
    for (int kc = 0; kc < 2; kc++) {
#pragma unroll
        for (int i = 0; i < 4; i++) {
            int rm = wm + i * 16 + l16;
            offA[kc][i] = rm * 64 + (((kc * 4 + quad) ^ (rm & 7)) * 8);
        }
#pragma unroll
        for (int j = 0; j < 2; j++) {
            int rn = wn + j * 16 + l16;
            offB[kc][j] = rn * 64 + (((kc * 4 + quad) ^ (rn & 7)) * 8);
        }
    }

    f32x4 acc[4][2] = {};

    // prologue: stage tile 0 into buf 0
#pragma unroll
    for (int t = 0; t < 4; t++) { gll16(gA[t], &sA[0][laOff[t]]); gA[t] += 64; }
#pragma unroll
    for (int t = 0; t < 2; t++) { gll16(gB[t], &sB[0][lbOff[t]]); gB[t] += 64; }
    __syncthreads();   // per-wave vmcnt(0) drain, then join

    int bsel = 0;
    for (int k0 = 0; k0 < K; k0 += 64) {
        const int ns = bsel ^ 1;
        // stage tile k0+64 into the other buffer (in flight under compute)
        if (k0 + 64 < K) {
#pragma unroll
            for (int t = 0; t < 4; t++) { gll16(gA[t], &sA[ns][laOff[t]]); gA[t] += 64; }
#pragma unroll
            for (int t = 0; t < 2; t++) { gll16(gB[t], &sB[ns][lbOff[t]]); gB[t] += 64; }
        }

#pragma unroll
        for (int kc = 0; kc < 2; kc++) {
            bf16x8 af[4], bfv[2];
#pragma unroll
            for (int i = 0; i < 4; i++) af[i] = *(bf16x8*)&sA[bsel][offA[kc][i]];
#pragma unroll
            for (int j = 0; j < 2; j++) bfv[j] = *(bf16x8*)&sB[bsel][offB[kc][j]];
#pragma unroll
            for (int i = 0; i < 4; i++)
#pragma unroll
                for (int j = 0; j < 2; j++)
                    acc[i][j] = __builtin_amdgcn_mfma_f32_16x16x32_bf16(af[i], bfv[j], acc[i][j], 0, 0, 0);
        }

        __syncthreads();   // staged buf[ns] landed; buf[bsel] reads done
        bsel = ns;
    }

#pragma unroll
    for (int i = 0; i < 4; i++) {
        int rowb = m0 + wm + i * 16 + quad * 4;
#pragma unroll
        for (int j = 0; j < 2; j++) {
            int col = n0 + wn + j * 16 + l16;
#pragma unroll
            for (int r = 0; r < 4; r++) {
                float v = acc[i][j][r];
                int row = rowb + r;
                if (MODE == 0) {
                    C[(size_t)row * N + col] = (CT)v;
                } else {
                    if (col < 2048)      C[(size_t)row * 2048 + col] = (CT)v;
                    else if (col < 2560) CkP[(size_t)row * 512 + (col - 2048)] = (bf16_t)v;
                    else                 CvtP[(size_t)(col - 2560) * S_LEN + row] = (bf16_t)v;
                }
            }
        }
    }
}

// ---------------------------------------------------------------------------
// Fused RoPE over q (16 heads) and k (4 heads): grid (S, 5), block 128.
// ---------------------------------------------------------------------------
__global__ void rope_all(bf16_t* __restrict__ Qh, bf16_t* __restrict__ Kh,
                         const float* __restrict__ cosb, const float* __restrict__ sinb)
{
    int s = blockIdx.x;
    int grp = blockIdx.y;
    int sub = threadIdx.x >> 5;
    int i = threadIdx.x & 31;
    bf16_t* row = (grp < 4) ? (Qh + ((size_t)s * NH + grp * 4 + sub) * HD)
                            : (Kh + ((size_t)s * NKV + sub) * HD);
    float x0 = (float)row[2 * i];
    float x1 = (float)row[2 * i + 1];
    float p0 = (float)row[64 + 2 * i];
    float p1 = (float)row[64 + 2 * i + 1];
    float c0 = cosb[s * HD + 2 * i];
    float c1 = cosb[s * HD + 2 * i + 1];
    float n0 = sinb[s * HD + 2 * i];
    float n1 = sinb[s * HD + 2 * i + 1];
    float r0 = -x1, r1 = x0;
    row[2 * i]          = (bf16_t)(r0 * c0 + p0 * n0);
    row[2 * i + 1]      = (bf16_t)(r1 * c1 + p1 * n1);
    row[64 + 2 * i]     = (bf16_t)(-r0 * n0 + p0 * c0);
    row[64 + 2 * i + 1] = (bf16_t)(-r1 * n1 + p1 * c1);
}

// ---------------------------------------------------------------------------
// Flash attention v10 (unchanged, verified): paired-triangle chunks.
// Pair p with 31-p = 33 tile-units; 4 chunks of 9/8/8/8 -> grid (64,4) =
// 256 blocks = 1/CU, every CU <= 9 units. Straddling chunk flushes its
// partial mid-chunk (second slot 64+p). 90 KB LDS full dbuf, 1 barrier/iter.
// ---------------------------------------------------------------------------
__global__ __launch_bounds__(512, 1) void flash_attn10(
    const bf16_t* __restrict__ Q,   // S x (NH*HD)
    const bf16_t* __restrict__ Kb,  // S x (NKV*HD)
    const bf16_t* __restrict__ VT,  // (NKV*HD) x S
    bf16_t* __restrict__ OpD,       // partial slots 0..255 (d_out, 64KB each)
    bf16_t* __restrict__ OpX,       // partial slots 256..319 (ws)
    float* __restrict__ lpart,      // 320 x 256 fp32
    int S)
{
    __shared__ __align__(16) bf16_t sK[2][64 * 136];   // 34.8 KB (dbuf)
    __shared__ __align__(16) bf16_t sVT[2][128 * 72];  // 36.9 KB (dbuf)
    __shared__ __align__(16) bf16_t sP[8][16 * 72];    // 18.4 KB, wave-private

    const int c   = blockIdx.x;          // chunk 0..63
    const int kvh = blockIdx.y;
    const int p   = c >> 2, sub = c & 3; // pair p: qtA=p, qtB=31-p
    const int ts   = (33 * sub + 3) >> 2;    // chunk t-range [ts, tend)
    const int tend = (33 * sub + 36) >> 2;   // sizes 9,8,8,8 over t=0..32
    const int tA   = p + 1;                  // t < tA -> qtA, else qtB

    const int tid = threadIdx.x, lane = tid & 63, wave = tid >> 6;
    const int l16 = lane & 15, quad = lane >> 4;
    const int rowg = wave & 3;                    // q-row group
    const int h0   = kvh * 4 + (wave >> 2) * 2;   // this wave's 2 heads
    const float scale = 0.08838834764831845f;     // 1/sqrt(128)

    // staging: 1024 16B-chunks per tile, 512 threads -> 2 chunks each
    int krow[2], kcol[2], vrow[2], vcol[2];
#pragma unroll
    for (int it = 0; it < 2; it++) {
        int cc = tid + 512 * it;
        krow[it] = cc >> 4; kcol[it] = (cc & 15) * 8;
        vrow[it] = cc >> 3; vcol[it] = (cc & 7) * 8;
    }

    // Up to 2 segments: first = A-part (or whole-B chunk), second = B-part
    // of a straddling chunk.
#pragma unroll
    for (int sI = 0; sI < 2; sI++) {
        int st0, st1, sqt, ssl;
        if (sI == 0) {
            if (ts < tA) { st0 = ts; st1 = (tend < tA ? tend : tA); sqt = p;      ssl = c; }
            else         { st0 = ts; st1 = tend;                    sqt = 31 - p; ssl = c; }
        } else {
            if (!(ts < tA && tend > tA)) break;
            st0 = tA; st1 = tend; sqt = 31 - p; ssl = 64 + p;
        }
        const int base = (sqt == p) ? 0 : tA;   // kt = t - base
        const int kb = st0 - base, ke = st1 - base;
        const int qt = sqt;
        const int q0 = qt * 64;
        const int qrow = q0 + rowg * 16 + l16;

        // Q fragments: 2 heads (B-operand of swapped QK)
        bf16x8 qf[2][4];
#pragma unroll
        for (int h = 0; h < 2; h++)
#pragma unroll
            for (int cc = 0; cc < 4; cc++)
                qf[h][cc] = *(const bf16x8*)&Q[(size_t)qrow * HID + (h0 + h) * HD + cc * 32 + quad * 8];

        f32x4 oacc[2][8] = {};
        float lsum[2] = {0.f, 0.f};

        // prologue: tile kb -> regs -> buf0; prefetch kb+1 into regs
        bf16x8 kpre[2], vpre[2];
#pragma unroll
        for (int it = 0; it < 2; it++) {
            kpre[it] = *(const bf16x8*)&Kb[(size_t)(kb * 64 + krow[it]) * (NKV * HD) + kvh * HD + kcol[it]];
            vpre[it] = *(const bf16x8*)&VT[((size_t)kvh * HD + vrow[it]) * S + kb * 64 + vcol[it]];
        }
#pragma unroll
        for (int it = 0; it < 2; it++) {
            *(bf16x8*)&sK[0][krow[it] * 136 + kcol[it]] = kpre[it];
            *(bf16x8*)&sVT[0][vrow[it] * 72 + vcol[it]] = vpre[it];
        }
        if (kb + 1 < ke) {
            const int t1 = (kb + 1) * 64;
#pragma unroll
            for (int it = 0; it < 2; it++) {
                kpre[it] = *(const bf16x8*)&Kb[(size_t)(t1 + krow[it]) * (NKV * HD) + kvh * HD + kcol[it]];
                vpre[it] = *(const bf16x8*)&VT[((size_t)kvh * HD + vrow[it]) * S + t1 + vcol[it]];
            }
        }
        __syncthreads();

        int sel = 0;
        for (int kt = kb; kt < ke; kt++) {
            const int t0 = kt * 64;
            const int ns = sel ^ 1;

            // stage tile kt+1 into the other buffers (overlaps compute)
            if (kt + 1 < ke) {
#pragma unroll
                for (int it = 0; it < 2; it++) {
                    *(bf16x8*)&sK[ns][krow[it] * 136 + kcol[it]] = kpre[it];
                    *(bf16x8*)&sVT[ns][vrow[it] * 72 + vcol[it]] = vpre[it];
                }
                if (kt + 2 < ke) {
                    const int t2 = t0 + 128;
#pragma unroll
                    for (int it = 0; it < 2; it++) {
                        kpre[it] = *(const bf16x8*)&Kb[(size_t)(t2 + krow[it]) * (NKV * HD) + kvh * HD + kcol[it]];
                        vpre[it] = *(const bf16x8*)&VT[((size_t)kvh * HD + vrow[it]) * S + t2 + vcol[it]];
                    }
                }
            }

            // ---- QK^T (swapped): nt outer, kf read once, 2 heads share ----
            f32x4 sc[2][4];   // [h][nt]
            __builtin_amdgcn_s_setprio(1);
#pragma unroll
            for (int nt = 0; nt < 4; nt++) {
                bf16x8 kf[4];
#pragma unroll
                for (int cc = 0; cc < 4; cc++)
                    kf[cc] = *(bf16x8*)&sK[sel][(nt * 16 + l16) * 136 + cc * 32 + quad * 8];
#pragma unroll
                for (int h = 0; h < 2; h++) {
                    f32x4 d = {};
#pragma unroll
                    for (int cc = 0; cc < 4; cc++)
                        d = __builtin_amdgcn_mfma_f32_16x16x32_bf16(kf[cc], qf[h][cc], d, 0, 0, 0);
                    sc[h][nt] = d;
                }
            }
            __builtin_amdgcn_s_setprio(0);

            // ---- exp + packed P write + A-frag read (wave-private sP) ----
            bf16x8 pa[2][2];
            if (kt == qt) {
#pragma unroll
                for (int h = 0; h < 2; h++) {
#pragma unroll
                    for (int nt = 0; nt < 4; nt++) {
                        const int tbk = t0 + nt * 16 + quad * 4;
                        bf16x4 pk;
#pragma unroll
                        for (int r = 0; r < 4; r++) {
                            float pv = (tbk + r <= qrow) ? __expf(sc[h][nt][r] * scale) : 0.0f;
                            lsum[h] += pv;
                            pk[r] = (bf16_t)pv;
                        }
                        *(bf16x4*)&sP[wave][l16 * 72 + nt * 16 + quad * 4] = pk;
                    }
#pragma unroll
                    for (int kc = 0; kc < 2; kc++)
                        pa[h][kc] = *(bf16x8*)&sP[wave][l16 * 72 + kc * 32 + quad * 8];
                }
            } else {
#pragma unroll
                for (int h = 0; h < 2; h++) {
#pragma unroll
                    for (int nt = 0; nt < 4; nt++) {
                        bf16x4 pk;
#pragma unroll
                        for (int r = 0; r < 4; r++) {
                            float pv = __expf(sc[h][nt][r] * scale);
                            lsum[h] += pv;
                            pk[r] = (bf16_t)pv;
                        }
                        *(bf16x4*)&sP[wave][l16 * 72 + nt * 16 + quad * 4] = pk;
                    }
#pragma unroll
                    for (int kc = 0; kc < 2; kc++)
                        pa[h][kc] = *(bf16x8*)&sP[wave][l16 * 72 + kc * 32 + quad * 8];
                }
            }

            // ---- PV: dt outer, vf read once, 2 heads share it ----
            __builtin_amdgcn_s_setprio(1);
#pragma unroll
            for (int dt = 0; dt < 8; dt++)
#pragma unroll
                for (int kc = 0; kc < 2; kc++) {
                    bf16x8 vf = *(bf16x8*)&sVT[sel][(dt * 16 + l16) * 72 + kc * 32 + quad * 8];
#pragma unroll
                    for (int h = 0; h < 2; h++)
                        oacc[h][dt] = __builtin_amdgcn_mfma_f32_16x16x32_bf16(pa[h][kc], vf, oacc[h][dt], 0, 0, 0);
                }
            __builtin_amdgcn_s_setprio(0);

            __syncthreads();   // buf[ns] writes visible; buf[sel] reads done
            sel = ns;
        }

        // epilogue: store UNNORMALIZED partial O + partial l into slot sg.
        // Slot layout: [64 rows][4 local heads][128 cols] bf16 (64 KB).
        const int sg = kvh * 80 + ssl;
        bf16_t* Op = (sg < 256) ? (OpD + (size_t)sg * 32768)
                                : (OpX + (size_t)(sg - 256) * 32768);
#pragma unroll
        for (int h = 0; h < 2; h++) {
            const int hl = (wave >> 2) * 2 + h;    // kvh-local head 0..3
            float lr = lsum[h];
            lr += __shfl_xor(lr, 16, 64);
            lr += __shfl_xor(lr, 32, 64);   // lane L: l for row offset L&15
            if (quad == 0)
                lpart[(size_t)sg * 256 + (rowg * 16 + l16) * 4 + hl] = lr;
#pragma unroll
            for (int r = 0; r < 4; r++) {
                int rr = rowg * 16 + quad * 4 + r;   // row within tile
#pragma unroll
                for (int dt = 0; dt < 8; dt++)
                    Op[((size_t)rr * 4 + hl) * 128 + dt * 16 + l16] =
                        (bf16_t)(oacc[h][dt][r]);
            }
        }
        // next segment (if any) restages buf0; all LDS reads of this segment
        // completed before the loop's final barrier.
    }
}

// ---------------------------------------------------------------------------
// Combine: oh[s,h,:] = (sum O_slot) / (sum l_slot) over the <=4 slots that
// contributed to q-tile qt = s>>6. Slot enumeration mirrors flash_attn10.
// ---------------------------------------------------------------------------
__global__ __launch_bounds__(256) void flash_combine10(
    const bf16_t* __restrict__ OpD, const bf16_t* __restrict__ OpX,
    const float* __restrict__ lpart, bf16_t* __restrict__ oh)
{
    int i = (blockIdx.x * 256 + threadIdx.x) * 8;
    int s = i >> 11;            // row (2048 cols)
    int h = (i >> 7) & 15;      // head
    int col = i & 127;
    int qt = s >> 6;
    int base80 = (h >> 2) * 80;
    int roff = (s & 63) * 4 + (h & 3);

    int sl[4]; int nsl = 0;
    if (qt <= 15) {
        int pr = qt;
#pragma unroll
        for (int sub = 0; sub < 4; sub++) {
            int tss = (33 * sub + 3) >> 2;
            if (tss < qt + 1) sl[nsl++] = pr * 4 + sub;
        }
    } else {
        int pr = 31 - qt, tAh = pr + 1;
#pragma unroll
        for (int sub = 0; sub < 4; sub++) {
            int tss = (33 * sub + 3) >> 2;
            int ten = (33 * sub + 36) >> 2;
            if (ten > tAh) sl[nsl++] = (tss < tAh) ? 64 + pr : pr * 4 + sub;
        }
    }

    float acc[8] = {0.f, 0.f, 0.f, 0.f, 0.f, 0.f, 0.f, 0.f};
    float l = 0.f;
    for (int ci = 0; ci < nsl; ci++) {
        int sg = base80 + sl[ci];
        const bf16_t* P = (sg < 256) ? (OpD + (size_t)sg * 32768)
                                     : (OpX + (size_t)(sg - 256) * 32768);
        bf16x8 a = *(const bf16x8*)&P[(size_t)roff * 128 + col];
#pragma unroll
        for (int j = 0; j < 8; j++) acc[j] += (float)a[j];
        l += lpart[(size_t)sg * 256 + roff];
    }
    float inv = 1.0f / l;
    bf16x8 o;
#pragma unroll
    for (int j = 0; j < 8; j++)
        o[j] = (bf16_t)(acc[j] * inv);
    *(bf16x8*)&oh[i] = o;
}

// ---------------------------------------------------------------------------
extern "C" void kernel_launch(void* const* d_in, const int* in_sizes, int n_in,
                              void* d_out, int out_size, void* d_ws, size_t ws_size,
                              hipStream_t stream)
{
    const float* x    = (const float*)d_in[0];
    const float* cosb = (const float*)d_in[1];
    const float* sinb = (const float*)d_in[2];
    const float* wq   = (const float*)d_in[3];
    const float* wk   = (const float*)d_in[4];
    const float* wv   = (const float*)d_in[5];
    const float* wo   = (const float*)d_in[6];
    float* out = (float*)d_out;

    // Workspace (28.5 MB -- proven envelope):
    char* ws = (char*)d_ws;
    bf16_t* wb = (bf16_t*)(ws);                              // 0..12 MB: [wq;wk;wv] bf16 (reused for wo)
    bf16_t* qh = (bf16_t*)(ws + (size_t)12 * 1024 * 1024);   // 12..20 MB: q / attn-out
    bf16_t* kh = (bf16_t*)(ws + (size_t)20 * 1024 * 1024);   // 20..22 MB: k
    bf16_t* vT = (bf16_t*)(ws + (size_t)22 * 1024 * 1024);   // 22..24 MB: v^T
    float*  lp = (float*) (ws + (size_t)24 * 1024 * 1024);   // 24..24.32 MB: partial l (320x256 f32)
    bf16_t* opx = (bf16_t*)(ws + (size_t)24 * 1024 * 1024 + 512 * 1024); // 24.5..28.5 MB: slots 256..319
    // d_out (16 MB) doubles as scratch: x bf16 (steps 1-2), then partial
    // slots 0..255 (steps 5-6).
    bf16_t* xb  = (bf16_t*)d_out;
    bf16_t* opd = (bf16_t*)d_out;

    const int NX = S_LEN * HID;   // 4 Mi

    // 1) x + [wq|wk|wv] fp32 -> bf16 in one pass
    cvt_all<<<10 * 1024 * 1024 / (256 * 8), 256, 0, stream>>>(
        x, wq, wk, wv, xb, wb);

    // 2) fused QKV GEMM (2-phase dbuf), routed outputs. 768 blocks = 3/CU.
    gemm128x64<1, bf16_t><<<dim3(48, 16), 256, 0, stream>>>(xb, wb, qh, kh, vT, 3072, HID);

    // 3) RoPE on q + k
    rope_all<<<dim3(S_LEN, 5), 128, 0, stream>>>(qh, kh, cosb, sinb);

    // 4) wo -> bf16 into wb (freed by step 2)
    cvt_f32_bf16<<<NX / (256 * 8), 256, 0, stream>>>(wo, wb, NX);

    // 5) flash attention v10: paired-triangle chunks, 256 blocks = 1/CU.
    flash_attn10<<<dim3(64, NKV), 512, 0, stream>>>(qh, kh, vT, opd, opx, lp, S_LEN);

    // 6) combine partial slots -> qh (attn output, normalized bf16)
    flash_combine10<<<NX / (256 * 8), 256, 0, stream>>>(opd, opx, lp, qh);

    // 7) out = attn_out @ wo^T -> fp32 d_out (2-phase dbuf). 512 blocks = 2/CU.
    gemm128x64<0, float><<<dim3(32, 16), 256, 0, stream>>>(qh, wb, out, nullptr, nullptr, HID, HID);
}

// Round 7
// 212.886 us; speedup vs baseline: 1.6226x; 1.0002x over previous
//
#include <hip/hip_runtime.h>
#include <hip/hip_bf16.h>

// Shapes (fixed): B=1, S=2048, HID=2048, NH=16, NKV=4, HD=128
// Inputs: fp32. Output: fp32. Internal compute: bf16 MFMA, fp32 accumulate.
typedef __bf16 bf16_t;
typedef __attribute__((ext_vector_type(8))) __bf16 bf16x8;
typedef __attribute__((ext_vector_type(4))) __bf16 bf16x4;
typedef __attribute__((ext_vector_type(4))) float f32x4;

#define S_LEN 2048
#define HID 2048
#define NH 16
#define NKV 4
#define HD 128

__device__ __forceinline__ void gll16(const bf16_t* g, bf16_t* l) {
    __builtin_amdgcn_global_load_lds(
        (const __attribute__((address_space(1))) unsigned int*)g,
        (__attribute__((address_space(3))) unsigned int*)l, 16, 0, 0);
}

__device__ __forceinline__ bf16x8 cvt2x4(float4 a, float4 b) {
    bf16x8 o;
    o[0]=(bf16_t)a.x; o[1]=(bf16_t)a.y; o[2]=(bf16_t)a.z; o[3]=(bf16_t)a.w;
    o[4]=(bf16_t)b.x; o[5]=(bf16_t)b.y; o[6]=(bf16_t)b.z; o[7]=(bf16_t)b.w;
    return o;
}

// ---------------------------------------------------------------------------
// Single fused conversion pass: x (4Mi) -> xb, [wq|wk|wv] (6Mi) -> wb,
// wo (4Mi) -> wob. 14Mi elems, 8/thread, 7168 blocks. (ws is 256 MB --
// the harness's 262144 KB fills prove it -- so wob at 28.5 MB is safe.)
// ---------------------------------------------------------------------------
__global__ __launch_bounds__(256) void cvt_all(
    const float* __restrict__ x,  const float* __restrict__ wq,
    const float* __restrict__ wk, const float* __restrict__ wv,
    const float* __restrict__ wo, bf16_t* __restrict__ xb,
    bf16_t* __restrict__ wb, bf16_t* __restrict__ wob)
{
    const size_t M = 1024 * 1024;
    size_t g = ((size_t)blockIdx.x * 256 + threadIdx.x) * 8;
    const float* src; bf16_t* dst; size_t soff, doff;
    if (g < 4 * M) {
        src = x; dst = xb; soff = g; doff = g;
    } else if (g < 10 * M) {
        size_t w = g - 4 * M; dst = wb; doff = w;
        if (w < 4 * M)      { src = wq; soff = w; }
        else if (w < 5 * M) { src = wk; soff = w - 4 * M; }
        else                { src = wv; soff = w - 5 * M; }
    } else {
        src = wo; dst = wob; soff = g - 10 * M; doff = soff;
    }
    float4 a = *(const float4*)&src[soff];
    float4 b = *(const float4*)&src[soff + 4];
    *(bf16x8*)&dst[doff] = cvt2x4(a, b);
}

// ---------------------------------------------------------------------------
// NT GEMM, tile 128x64, 2-phase double-buffered (unchanged from round 6).
// QKV grid 48x16=768=3/CU, out grid 32x16=512=2/CU.
// MODE 0: C fp32 row-major. MODE 1: qkv routing (C=q bf16 / Ck / Cvt^T).
// ---------------------------------------------------------------------------
template<int MODE, typename CT>
__global__ __launch_bounds__(256, 4) void gemm128x64(
    const bf16_t* __restrict__ A, const bf16_t* __restrict__ B,
    CT* __restrict__ C, bf16_t* __restrict__ CkP, bf16_t* __restrict__ CvtP,
    int N, int K)
{
    __shared__ __align__(16) bf16_t sA[2][128 * 64];   // 32 KB
    __shared__ __align__(16) bf16_t sB[2][64 * 64];    // 16 KB

    const int tid = threadIdx.x, lane = tid & 63, wave = tid >> 6;
    const int l16 = lane & 15, quad = lane >> 4;
    const int m0 = blockIdx.y * 128, n0 = blockIdx.x * 64;
    const int wm = (wave >> 1) * 64, wn = (wave & 1) * 32;

    const bf16_t* gA[4]; const bf16_t* gB[2];
    int laOff[4], lbOff[2];
#pragma unroll
    for (int t = 0; t < 4; t++) {
        int p = (wave * 4 + t) * 64 + lane;
        int row = p >> 3;
        int lc = (p & 7) ^ (row & 7);
        gA[t] = A + (size_t)(m0 + row) * K + lc * 8;
        laOff[t] = (wave * 4 + t) * 512;
    }
#pragma unroll
    for (int t = 0; t < 2; t++) {
        int p = (wave * 2 + t) * 64 + lane;
        int row = p >> 3;
        int lc = (p & 7) ^ (row & 7);
        gB[t] = B + (size_t)(n0 + row) * K + lc * 8;
        lbOff[t] = (wave * 2 + t) * 512;
    }

    int offA[2][4], offB[2][2];
#pragma unroll
    for (int kc = 0; kc < 2; kc++) {
#pragma unroll
        for (int i = 0; i < 4; i++) {
            int rm = wm + i * 16 + l16;
            offA[kc][i] = rm * 64 + (((kc * 4 + quad) ^ (rm & 7)) * 8);
        }
#pragma unroll
        for (int j = 0; j < 2; j++) {
            int rn = wn + j * 16 + l16;
            offB[kc][j] = rn * 64 + (((kc * 4 + quad) ^ (rn & 7)) * 8);
        }
    }

    f32x4 acc[4][2] = {};

    // prologue: stage tile 0 into buf 0
#pragma unroll
    for (int t = 0; t < 4; t++) { gll16(gA[t], &sA[0][laOff[t]]); gA[t] += 64; }
#pragma unroll
    for (int t = 0; t < 2; t++) { gll16(gB[t], &sB[0][lbOff[t]]); gB[t] += 64; }
    __syncthreads();

    int bsel = 0;
    for (int k0 = 0; k0 < K; k0 += 64) {
        const int ns = bsel ^ 1;
        if (k0 + 64 < K) {
#pragma unroll
            for (int t = 0; t < 4; t++) { gll16(gA[t], &sA[ns][laOff[t]]); gA[t] += 64; }
#pragma unroll
            for (int t = 0; t < 2; t++) { gll16(gB[t], &sB[ns][lbOff[t]]); gB[t] += 64; }
        }

#pragma unroll
        for (int kc = 0; kc < 2; kc++) {
            bf16x8 af[4], bfv[2];
#pragma unroll
            for (int i = 0; i < 4; i++) af[i] = *(bf16x8*)&sA[bsel][offA[kc][i]];
#pragma unroll
            for (int j = 0; j < 2; j++) bfv[j] = *(bf16x8*)&sB[bsel][offB[kc][j]];
#pragma unroll
            for (int i = 0; i < 4; i++)
#pragma unroll
                for (int j = 0; j < 2; j++)
                    acc[i][j] = __builtin_amdgcn_mfma_f32_16x16x32_bf16(af[i], bfv[j], acc[i][j], 0, 0, 0);
        }

        __syncthreads();
        bsel = ns;
    }

#pragma unroll
    for (int i = 0; i < 4; i++) {
        int rowb = m0 + wm + i * 16 + quad * 4;
#pragma unroll
        for (int j = 0; j < 2; j++) {
            int col = n0 + wn + j * 16 + l16;
#pragma unroll
            for (int r = 0; r < 4; r++) {
                float v = acc[i][j][r];
                int row = rowb + r;
                if (MODE == 0) {
                    C[(size_t)row * N + col] = (CT)v;
                } else {
                    if (col < 2048)      C[(size_t)row * 2048 + col] = (CT)v;
                    else if (col < 2560) CkP[(size_t)row * 512 + (col - 2048)] = (bf16_t)v;
                    else                 CvtP[(size_t)(col - 2560) * S_LEN + row] = (bf16_t)v;
                }
            }
        }
    }
}

// ---------------------------------------------------------------------------
// Fused RoPE over q (16 heads) and k (4 heads): grid (S, 5), block 128.
// ---------------------------------------------------------------------------
__global__ void rope_all(bf16_t* __restrict__ Qh, bf16_t* __restrict__ Kh,
                         const float* __restrict__ cosb, const float* __restrict__ sinb)
{
    int s = blockIdx.x;
    int grp = blockIdx.y;
    int sub = threadIdx.x >> 5;
    int i = threadIdx.x & 31;
    bf16_t* row = (grp < 4) ? (Qh + ((size_t)s * NH + grp * 4 + sub) * HD)
                            : (Kh + ((size_t)s * NKV + sub) * HD);
    float x0 = (float)row[2 * i];
    float x1 = (float)row[2 * i + 1];
    float p0 = (float)row[64 + 2 * i];
    float p1 = (float)row[64 + 2 * i + 1];
    float c0 = cosb[s * HD + 2 * i];
    float c1 = cosb[s * HD + 2 * i + 1];
    float n0 = sinb[s * HD + 2 * i];
    float n1 = sinb[s * HD + 2 * i + 1];
    float r0 = -x1, r1 = x0;
    row[2 * i]          = (bf16_t)(r0 * c0 + p0 * n0);
    row[2 * i + 1]      = (bf16_t)(r1 * c1 + p1 * n1);
    row[64 + 2 * i]     = (bf16_t)(-r0 * n0 + p0 * c0);
    row[64 + 2 * i + 1] = (bf16_t)(-r1 * n1 + p1 * c1);
}

// ---------------------------------------------------------------------------
// Flash attention v11: 4 waves x 4 HEADS each (was 8 waves x 2 heads).
// The kernel is LDS-pipe-bound per CU: all waves read identical sK/sVT
// fragments, amortized over heads-per-wave. 4 heads/wave halves the
// kf/vf read total per block-iter: ~352 -> ~224 b128-eq (~-36% on the
// binding pipe). VGPR grows to ~290 (oacc[4][8]=128 + qf[4][4]=64) ->
// 1 wave/SIMD under __launch_bounds__(256,1) (budget 512, NO spill; the
// 4 waves drift across QK/exp/PV phases and keep the shared LDS pipe fed).
// Same paired-triangle chunk geometry (grid (64,4)=256 blocks=1/CU, <=9
// units/CU), same verified dataflow and slot/combine layout as v10.
// ---------------------------------------------------------------------------
__global__ __launch_bounds__(256, 1) void flash_attn11(
    const bf16_t* __restrict__ Q,   // S x (NH*HD)
    const bf16_t* __restrict__ Kb,  // S x (NKV*HD)
    const bf16_t* __restrict__ VT,  // (NKV*HD) x S
    bf16_t* __restrict__ OpD,       // partial slots 0..255 (d_out, 64KB each)
    bf16_t* __restrict__ OpX,       // partial slots 256..319 (ws)
    float* __restrict__ lpart,      // 320 x 256 fp32
    int S)
{
    __shared__ __align__(16) bf16_t sK[2][64 * 136];   // 34.8 KB (dbuf)
    __shared__ __align__(16) bf16_t sVT[2][128 * 72];  // 36.9 KB (dbuf)
    __shared__ __align__(16) bf16_t sP[4][16 * 72];    //  9.2 KB, wave-private

    const int c   = blockIdx.x;          // chunk 0..63
    const int kvh = blockIdx.y;
    const int p   = c >> 2, sub = c & 3; // pair p: qtA=p, qtB=31-p
    const int ts   = (33 * sub + 3) >> 2;    // chunk t-range [ts, tend)
    const int tend = (33 * sub + 36) >> 2;   // sizes 9,8,8,8 over t=0..32
    const int tA   = p + 1;                  // t < tA -> qtA, else qtB

    const int tid = threadIdx.x, lane = tid & 63, wave = tid >> 6;
    const int l16 = lane & 15, quad = lane >> 4;
    const int rowg = wave;                        // q-row group 0..3
    const int h0   = kvh * 4;                     // 4 heads per wave
    const float scale = 0.08838834764831845f;     // 1/sqrt(128)

    // staging: 1024 16B-chunks per tile, 256 threads -> 4 chunks each
    int krow[4], kcol[4], vrow[4], vcol[4];
#pragma unroll
    for (int it = 0; it < 4; it++) {
        int cc = tid + 256 * it;
        krow[it] = cc >> 4; kcol[it] = (cc & 15) * 8;
        vrow[it] = cc >> 3; vcol[it] = (cc & 7) * 8;
    }

    // Up to 2 segments: first = A-part (or whole-B chunk), second = B-part
    // of a straddling chunk.
#pragma unroll
    for (int sI = 0; sI < 2; sI++) {
        int st0, st1, sqt, ssl;
        if (sI == 0) {
            if (ts < tA) { st0 = ts; st1 = (tend < tA ? tend : tA); sqt = p;      ssl = c; }
            else         { st0 = ts; st1 = tend;                    sqt = 31 - p; ssl = c; }
        } else {
            if (!(ts < tA && tend > tA)) break;
            st0 = tA; st1 = tend; sqt = 31 - p; ssl = 64 + p;
        }
        const int base = (sqt == p) ? 0 : tA;   // kt = t - base
        const int kb = st0 - base, ke = st1 - base;
        const int qt = sqt;
        const int q0 = qt * 64;
        const int qrow = q0 + rowg * 16 + l16;

        // Q fragments: 4 heads (B-operand of swapped QK)
        bf16x8 qf[4][4];
#pragma unroll
        for (int h = 0; h < 4; h++)
#pragma unroll
            for (int cc = 0; cc < 4; cc++)
                qf[h][cc] = *(const bf16x8*)&Q[(size_t)qrow * HID + (h0 + h) * HD + cc * 32 + quad * 8];

        f32x4 oacc[4][8] = {};
        float lsum[4] = {0.f, 0.f, 0.f, 0.f};

        // prologue: tile kb -> regs -> buf0; prefetch kb+1 into regs
        bf16x8 kpre[4], vpre[4];
#pragma unroll
        for (int it = 0; it < 4; it++) {
            kpre[it] = *(const bf16x8*)&Kb[(size_t)(kb * 64 + krow[it]) * (NKV * HD) + kvh * HD + kcol[it]];
            vpre[it] = *(const bf16x8*)&VT[((size_t)kvh * HD + vrow[it]) * S + kb * 64 + vcol[it]];
        }
#pragma unroll
        for (int it = 0; it < 4; it++) {
            *(bf16x8*)&sK[0][krow[it] * 136 + kcol[it]] = kpre[it];
            *(bf16x8*)&sVT[0][vrow[it] * 72 + vcol[it]] = vpre[it];
        }
        if (kb + 1 < ke) {
            const int t1 = (kb + 1) * 64;
#pragma unroll
            for (int it = 0; it < 4; it++) {
                kpre[it] = *(const bf16x8*)&Kb[(size_t)(t1 + krow[it]) * (NKV * HD) + kvh * HD + kcol[it]];
                vpre[it] = *(const bf16x8*)&VT[((size_t)kvh * HD + vrow[it]) * S + t1 + vcol[it]];
            }
        }
        __syncthreads();

        int sel = 0;
        for (int kt = kb; kt < ke; kt++) {
            const int t0 = kt * 64;
            const int ns = sel ^ 1;

            // stage tile kt+1 into the other buffers (overlaps compute)
            if (kt + 1 < ke) {
#pragma unroll
                for (int it = 0; it < 4; it++) {
                    *(bf16x8*)&sK[ns][krow[it] * 136 + kcol[it]] = kpre[it];
                    *(bf16x8*)&sVT[ns][vrow[it] * 72 + vcol[it]] = vpre[it];
                }
                if (kt + 2 < ke) {
                    const int t2 = t0 + 128;
#pragma unroll
                    for (int it = 0; it < 4; it++) {
                        kpre[it] = *(const bf16x8*)&Kb[(size_t)(t2 + krow[it]) * (NKV * HD) + kvh * HD + kcol[it]];
                        vpre[it] = *(const bf16x8*)&VT[((size_t)kvh * HD + vrow[it]) * S + t2 + vcol[it]];
                    }
                }
            }

            // ---- QK^T (swapped): nt outer, kf read once, 4 heads share ----
            f32x4 sc[4][4];   // [h][nt]
            __builtin_amdgcn_s_setprio(1);
#pragma unroll
            for (int nt = 0; nt < 4; nt++) {
                bf16x8 kf[4];
#pragma unroll
                for (int cc = 0; cc < 4; cc++)
                    kf[cc] = *(bf16x8*)&sK[sel][(nt * 16 + l16) * 136 + cc * 32 + quad * 8];
#pragma unroll
                for (int h = 0; h < 4; h++) {
                    f32x4 d = {};
#pragma unroll
                    for (int cc = 0; cc < 4; cc++)
                        d = __builtin_amdgcn_mfma_f32_16x16x32_bf16(kf[cc], qf[h][cc], d, 0, 0, 0);
                    sc[h][nt] = d;
                }
            }
            __builtin_amdgcn_s_setprio(0);

            // ---- exp + packed P write + A-frag read (wave-private sP) ----
            bf16x8 pa[4][2];
            if (kt == qt) {
#pragma unroll
                for (int h = 0; h < 4; h++) {
#pragma unroll
                    for (int nt = 0; nt < 4; nt++) {
                        const int tbk = t0 + nt * 16 + quad * 4;
                        bf16x4 pk;
#pragma unroll
                        for (int r = 0; r < 4; r++) {
                            float pv = (tbk + r <= qrow) ? __expf(sc[h][nt][r] * scale) : 0.0f;
                            lsum[h] += pv;
                            pk[r] = (bf16_t)pv;
                        }
                        *(bf16x4*)&sP[wave][l16 * 72 + nt * 16 + quad * 4] = pk;
                    }
#pragma unroll
                    for (int kc = 0; kc < 2; kc++)
                        pa[h][kc] = *(bf16x8*)&sP[wave][l16 * 72 + kc * 32 + quad * 8];
                }
            } else {
#pragma unroll
                for (int h = 0; h < 4; h++) {
#pragma unroll
                    for (int nt = 0; nt < 4; nt++) {
                        bf16x4 pk;
#pragma unroll
                        for (int r = 0; r < 4; r++) {
                            float pv = __expf(sc[h][nt][r] * scale);
                            lsum[h] += pv;
                            pk[r] = (bf16_t)pv;
                        }
                        *(bf16x4*)&sP[wave][l16 * 72 + nt * 16 + quad * 4] = pk;
                    }
#pragma unroll
                    for (int kc = 0; kc < 2; kc++)
                        pa[h][kc] = *(bf16x8*)&sP[wave][l16 * 72 + kc * 32 + quad * 8];
                }
            }

            // ---- PV: dt outer, vf read once, 4 heads share it ----
            __builtin_amdgcn_s_setprio(1);
#pragma unroll
            for (int dt = 0; dt < 8; dt++)
#pragma unroll
                for (int kc = 0; kc < 2; kc++) {
                    bf16x8 vf = *(bf16x8*)&sVT[sel][(dt * 16 + l16) * 72 + kc * 32 + quad * 8];
#pragma unroll
                    for (int h = 0; h < 4; h++)
                        oacc[h][dt] = __builtin_amdgcn_mfma_f32_16x16x32_bf16(pa[h][kc], vf, oacc[h][dt], 0, 0, 0);
                }
            __builtin_amdgcn_s_setprio(0);

            __syncthreads();   // buf[ns] writes visible; buf[sel] reads done
            sel = ns;
        }

        // epilogue: store UNNORMALIZED partial O + partial l into slot sg.
        // Slot layout: [64 rows][4 local heads][128 cols] bf16 (64 KB).
        const int sg = kvh * 80 + ssl;
        bf16_t* Op = (sg < 256) ? (OpD + (size_t)sg * 32768)
                                : (OpX + (size_t)(sg - 256) * 32768);
#pragma unroll
        for (int h = 0; h < 4; h++) {
            float lr = lsum[h];
            lr += __shfl_xor(lr, 16, 64);
            lr += __shfl_xor(lr, 32, 64);   // lane L: l for row offset L&15
            if (quad == 0)
                lpart[(size_t)sg * 256 + (rowg * 16 + l16) * 4 + h] = lr;
#pragma unroll
            for (int r = 0; r < 4; r++) {
                int rr = rowg * 16 + quad * 4 + r;   // row within tile
#pragma unroll
                for (int dt = 0; dt < 8; dt++)
                    Op[((size_t)rr * 4 + h) * 128 + dt * 16 + l16] =
                        (bf16_t)(oacc[h][dt][r]);
            }
        }
        // next segment (if any) restages buf0; all LDS reads of this segment
        // completed before the loop's final barrier.
    }
}

// ---------------------------------------------------------------------------
// Combine: oh[s,h,:] = (sum O_slot) / (sum l_slot) over the <=4 slots that
// contributed to q-tile qt = s>>6. Slot enumeration mirrors flash_attn11.
// ---------------------------------------------------------------------------
__global__ __launch_bounds__(256) void flash_combine10(
    const bf16_t* __restrict__ OpD, const bf16_t* __restrict__ OpX,
    const float* __restrict__ lpart, bf16_t* __restrict__ oh)
{
    int i = (blockIdx.x * 256 + threadIdx.x) * 8;
    int s = i >> 11;            // row (2048 cols)
    int h = (i >> 7) & 15;      // head
    int col = i & 127;
    int qt = s >> 6;
    int base80 = (h >> 2) * 80;
    int roff = (s & 63) * 4 + (h & 3);

    int sl[4]; int nsl = 0;
    if (qt <= 15) {
        int pr = qt;
#pragma unroll
        for (int sub = 0; sub < 4; sub++) {
            int tss = (33 * sub + 3) >> 2;
            if (tss < qt + 1) sl[nsl++] = pr * 4 + sub;
        }
    } else {
        int pr = 31 - qt, tAh = pr + 1;
#pragma unroll
        for (int sub = 0; sub < 4; sub++) {
            int tss = (33 * sub + 3) >> 2;
            int ten = (33 * sub + 36) >> 2;
            if (ten > tAh) sl[nsl++] = (tss < tAh) ? 64 + pr : pr * 4 + sub;
        }
    }

    float acc[8] = {0.f, 0.f, 0.f, 0.f, 0.f, 0.f, 0.f, 0.f};
    float l = 0.f;
    for (int ci = 0; ci < nsl; ci++) {
        int sg = base80 + sl[ci];
        const bf16_t* P = (sg < 256) ? (OpD + (size_t)sg * 32768)
                                     : (OpX + (size_t)(sg - 256) * 32768);
        bf16x8 a = *(const bf16x8*)&P[(size_t)roff * 128 + col];
#pragma unroll
        for (int j = 0; j < 8; j++) acc[j] += (float)a[j];
        l += lpart[(size_t)sg * 256 + roff];
    }
    float inv = 1.0f / l;
    bf16x8 o;
#pragma unroll
    for (int j = 0; j < 8; j++)
        o[j] = (bf16_t)(acc[j] * inv);
    *(bf16x8*)&oh[i] = o;
}

// ---------------------------------------------------------------------------
extern "C" void kernel_launch(void* const* d_in, const int* in_sizes, int n_in,
                              void* d_out, int out_size, void* d_ws, size_t ws_size,
                              hipStream_t stream)
{
    const float* x    = (const float*)d_in[0];
    const float* cosb = (const float*)d_in[1];
    const float* sinb = (const float*)d_in[2];
    const float* wq   = (const float*)d_in[3];
    const float* wk   = (const float*)d_in[4];
    const float* wv   = (const float*)d_in[5];
    const float* wo   = (const float*)d_in[6];
    float* out = (float*)d_out;

    // Workspace (32.5 MB of the 256 MB ws):
    char* ws = (char*)d_ws;
    bf16_t* wb = (bf16_t*)(ws);                              // 0..12 MB: [wq;wk;wv] bf16
    bf16_t* qh = (bf16_t*)(ws + (size_t)12 * 1024 * 1024);   // 12..20 MB: q / attn-out
    bf16_t* kh = (bf16_t*)(ws + (size_t)20 * 1024 * 1024);   // 20..22 MB: k
    bf16_t* vT = (bf16_t*)(ws + (size_t)22 * 1024 * 1024);   // 22..24 MB: v^T
    float*  lp = (float*) (ws + (size_t)24 * 1024 * 1024);   // 24..24.32 MB: partial l (320x256 f32)
    bf16_t* opx = (bf16_t*)(ws + (size_t)24 * 1024 * 1024 + 512 * 1024); // 24.5..28.5 MB: slots 256..319
    bf16_t* wob = (bf16_t*)(ws + (size_t)28 * 1024 * 1024 + 512 * 1024); // 28.5..32.5 MB: wo bf16
    // d_out (16 MB) doubles as scratch: x bf16 (steps 1-2), then partial
    // slots 0..255 (steps 4-5).
    bf16_t* xb  = (bf16_t*)d_out;
    bf16_t* opd = (bf16_t*)d_out;

    const int NX = S_LEN * HID;   // 4 Mi

    // 1) all fp32 -> bf16 conversions in one pass (x, wq|wk|wv, wo)
    cvt_all<<<14 * 1024 * 1024 / (256 * 8), 256, 0, stream>>>(
        x, wq, wk, wv, wo, xb, wb, wob);

    // 2) fused QKV GEMM (2-phase dbuf), routed outputs. 768 blocks = 3/CU.
    gemm128x64<1, bf16_t><<<dim3(48, 16), 256, 0, stream>>>(xb, wb, qh, kh, vT, 3072, HID);

    // 3) RoPE on q + k
    rope_all<<<dim3(S_LEN, 5), 128, 0, stream>>>(qh, kh, cosb, sinb);

    // 4) flash attention v11: 4 waves x 4 heads, 256 blocks = 1/CU.
    flash_attn11<<<dim3(64, NKV), 256, 0, stream>>>(qh, kh, vT, opd, opx, lp, S_LEN);

    // 5) combine partial slots -> qh (attn output, normalized bf16)
    flash_combine10<<<NX / (256 * 8), 256, 0, stream>>>(opd, opx, lp, qh);

    // 6) out = attn_out @ wo^T -> fp32 d_out (2-phase dbuf). 512 blocks = 2/CU.
    gemm128x64<0, float><<<dim3(32, 16), 256, 0, stream>>>(qh, wob, out, nullptr, nullptr, HID, HID);
}

// Round 8
// 211.257 us; speedup vs baseline: 1.6351x; 1.0077x over previous
//
#include <hip/hip_runtime.h>
#include <hip/hip_bf16.h>

// Shapes (fixed): B=1, S=2048, HID=2048, NH=16, NKV=4, HD=128
// Inputs: fp32. Output: fp32. Internal compute: bf16 MFMA, fp32 accumulate.
typedef __bf16 bf16_t;
typedef __attribute__((ext_vector_type(8))) __bf16 bf16x8;
typedef __attribute__((ext_vector_type(4))) __bf16 bf16x4;
typedef __attribute__((ext_vector_type(4))) float f32x4;

#define S_LEN 2048
#define HID 2048
#define NH 16
#define NKV 4
#define HD 128

__device__ __forceinline__ void gll16(const bf16_t* g, bf16_t* l) {
    __builtin_amdgcn_global_load_lds(
        (const __attribute__((address_space(1))) unsigned int*)g,
        (__attribute__((address_space(3))) unsigned int*)l, 16, 0, 0);
}

__device__ __forceinline__ bf16x8 cvt2x4(float4 a, float4 b) {
    bf16x8 o;
    o[0]=(bf16_t)a.x; o[1]=(bf16_t)a.y; o[2]=(bf16_t)a.z; o[3]=(bf16_t)a.w;
    o[4]=(bf16_t)b.x; o[5]=(bf16_t)b.y; o[6]=(bf16_t)b.z; o[7]=(bf16_t)b.w;
    return o;
}

// ---------------------------------------------------------------------------
// Single fused conversion pass: x (4Mi) -> xb, [wq|wk|wv] (6Mi) -> wb,
// wo (4Mi) -> wob. 14Mi elems, 8/thread.
// ---------------------------------------------------------------------------
__global__ __launch_bounds__(256) void cvt_all(
    const float* __restrict__ x,  const float* __restrict__ wq,
    const float* __restrict__ wk, const float* __restrict__ wv,
    const float* __restrict__ wo, bf16_t* __restrict__ xb,
    bf16_t* __restrict__ wb, bf16_t* __restrict__ wob)
{
    const size_t M = 1024 * 1024;
    size_t g = ((size_t)blockIdx.x * 256 + threadIdx.x) * 8;
    const float* src; bf16_t* dst; size_t soff, doff;
    if (g < 4 * M) {
        src = x; dst = xb; soff = g; doff = g;
    } else if (g < 10 * M) {
        size_t w = g - 4 * M; dst = wb; doff = w;
        if (w < 4 * M)      { src = wq; soff = w; }
        else if (w < 5 * M) { src = wk; soff = w - 4 * M; }
        else                { src = wv; soff = w - 5 * M; }
    } else {
        src = wo; dst = wob; soff = g - 10 * M; doff = soff;
    }
    float4 a = *(const float4*)&src[soff];
    float4 b = *(const float4*)&src[soff + 4];
    *(bf16x8*)&dst[doff] = cvt2x4(a, b);
}

// ---------------------------------------------------------------------------
// NT GEMM, tile 128x64, 2-phase double-buffered (unchanged, verified).
// QKV grid 48x16=768=3/CU, out grid 32x16=512=2/CU.
// MODE 0: C fp32 row-major. MODE 1: qkv routing (C=q bf16 / Ck / Cvt^T).
// ---------------------------------------------------------------------------
template<int MODE, typename CT>
__global__ __launch_bounds__(256, 4) void gemm128x64(
    const bf16_t* __restrict__ A, const bf16_t* __restrict__ B,
    CT* __restrict__ C, bf16_t* __restrict__ CkP, bf16_t* __restrict__ CvtP,
    int N, int K)
{
    __shared__ __align__(16) bf16_t sA[2][128 * 64];   // 32 KB
    __shared__ __align__(16) bf16_t sB[2][64 * 64];    // 16 KB

    const int tid = threadIdx.x, lane = tid & 63, wave = tid >> 6;
    const int l16 = lane & 15, quad = lane >> 4;
    const int m0 = blockIdx.y * 128, n0 = blockIdx.x * 64;
    const int wm = (wave >> 1) * 64, wn = (wave & 1) * 32;

    const bf16_t* gA[4]; const bf16_t* gB[2];
    int laOff[4], lbOff[2];
#pragma unroll
    for (int t = 0; t < 4; t++) {
        int p = (wave * 4 + t) * 64 + lane;
        int row = p >> 3;
        int lc = (p & 7) ^ (row & 7);
        gA[t] = A + (size_t)(m0 + row) * K + lc * 8;
        laOff[t] = (wave * 4 + t) * 512;
    }
#pragma unroll
    for (int t = 0; t < 2; t++) {
        int p = (wave * 2 + t) * 64 + lane;
        int row = p >> 3;
        int lc = (p & 7) ^ (row & 7);
        gB[t] = B + (size_t)(n0 + row) * K + lc * 8;
        lbOff[t] = (wave * 2 + t) * 512;
    }

    int offA[2][4], offB[2][2];
#pragma unroll
    for (int kc = 0; kc < 2; kc++) {
#pragma unroll
        for (int i = 0; i < 4; i++) {
            int rm = wm + i * 16 + l16;
            offA[kc][i] = rm * 64 + (((kc * 4 + quad) ^ (rm & 7)) * 8);
        }
#pragma unroll
        for (int j = 0; j < 2; j++) {
            int rn = wn + j * 16 + l16;
            offB[kc][j] = rn * 64 + (((kc * 4 + quad) ^ (rn & 7)) * 8);
        }
    }

    f32x4 acc[4][2] = {};

    // prologue: stage tile 0 into buf 0
#pragma unroll
    for (int t = 0; t < 4; t++) { gll16(gA[t], &sA[0][laOff[t]]); gA[t] += 64; }
#pragma unroll
    for (int t = 0; t < 2; t++) { gll16(gB[t], &sB[0][lbOff[t]]); gB[t] += 64; }
    __syncthreads();

    int bsel = 0;
    for (int k0 = 0; k0 < K; k0 += 64) {
        const int ns = bsel ^ 1;
        if (k0 + 64 < K) {
#pragma unroll
            for (int t = 0; t < 4; t++) { gll16(gA[t], &sA[ns][laOff[t]]); gA[t] += 64; }
#pragma unroll
            for (int t = 0; t < 2; t++) { gll16(gB[t], &sB[ns][lbOff[t]]); gB[t] += 64; }
        }

#pragma unroll
        for (int kc = 0; kc < 2; kc++) {
            bf16x8 af[4], bfv[2];
#pragma unroll
            for (int i = 0; i < 4; i++) af[i] = *(bf16x8*)&sA[bsel][offA[kc][i]];
#pragma unroll
            for (int j = 0; j < 2; j++) bfv[j] = *(bf16x8*)&sB[bsel][offB[kc][j]];
#pragma unroll
            for (int i = 0; i < 4; i++)
#pragma unroll
                for (int j = 0; j < 2; j++)
                    acc[i][j] = __builtin_amdgcn_mfma_f32_16x16x32_bf16(af[i], bfv[j], acc[i][j], 0, 0, 0);
        }

        __syncthreads();
        bsel = ns;
    }

#pragma unroll
    for (int i = 0; i < 4; i++) {
        int rowb = m0 + wm + i * 16 + quad * 4;
#pragma unroll
        for (int j = 0; j < 2; j++) {
            int col = n0 + wn + j * 16 + l16;
#pragma unroll
            for (int r = 0; r < 4; r++) {
                float v = acc[i][j][r];
                int row = rowb + r;
                if (MODE == 0) {
                    C[(size_t)row * N + col] = (CT)v;
                } else {
                    if (col < 2048)      C[(size_t)row * 2048 + col] = (CT)v;
                    else if (col < 2560) CkP[(size_t)row * 512 + (col - 2048)] = (bf16_t)v;
                    else                 CvtP[(size_t)(col - 2560) * S_LEN + row] = (bf16_t)v;
                }
            }
        }
    }
}

// ---------------------------------------------------------------------------
// RoPE on k only (q's RoPE is fused into attention's Q-fragment load).
// Grid (S, 1), block 128 = 4 heads x 32 pair-lanes.
// ---------------------------------------------------------------------------
__global__ void rope_k(bf16_t* __restrict__ Kh,
                       const float* __restrict__ cosb, const float* __restrict__ sinb)
{
    int s = blockIdx.x;
    int sub = threadIdx.x >> 5;
    int i = threadIdx.x & 31;
    bf16_t* row = Kh + ((size_t)s * NKV + sub) * HD;
    float x0 = (float)row[2 * i];
    float x1 = (float)row[2 * i + 1];
    float p0 = (float)row[64 + 2 * i];
    float p1 = (float)row[64 + 2 * i + 1];
    float c0 = cosb[s * HD + 2 * i];
    float c1 = cosb[s * HD + 2 * i + 1];
    float n0 = sinb[s * HD + 2 * i];
    float n1 = sinb[s * HD + 2 * i + 1];
    float r0 = -x1, r1 = x0;
    row[2 * i]          = (bf16_t)(r0 * c0 + p0 * n0);
    row[2 * i + 1]      = (bf16_t)(r1 * c1 + p1 * n1);
    row[64 + 2 * i]     = (bf16_t)(-r0 * n0 + p0 * c0);
    row[64 + 2 * i + 1] = (bf16_t)(-r1 * n1 + p1 * c1);
}

// ---------------------------------------------------------------------------
// Flash attention v12 = v11 (4 waves x 4 heads, paired-triangle chunks,
// grid (64,4)=256 blocks=1/CU) +:
//  a) Q-RoPE fused in-register at Q-fragment load: thread's chunks cc and
//     cc+2 hold d and d+64 for d = cc*32+quad*8+e, and (2i,2i+1) pairs are
//     adjacent elements -> RoPE needs no cross-lane traffic. cos/sin loaded
//     once per segment, shared by all 4 heads. Removes the q-pass of the
//     old rope kernel entirely (q stays un-roped in memory).
//  b) Per-(wave,head) sP buffers + batched write-then-read: all 16 P-writes
//     issue before any pa-read -> one lgkm drain instead of 4 serial
//     write->wait->read cycles per tile-iter. LDS 81 -> 108.5 KB (still
//     1 block/CU).
// Dataflow/slots/combine identical to the verified v10/v11.
// ---------------------------------------------------------------------------
__global__ __launch_bounds__(256, 1) void flash_attn12(
    const bf16_t* __restrict__ Q,   // S x (NH*HD), UN-roped
    const bf16_t* __restrict__ Kb,  // S x (NKV*HD), roped
    const bf16_t* __restrict__ VT,  // (NKV*HD) x S
    const float* __restrict__ cosb, const float* __restrict__ sinb,
    bf16_t* __restrict__ OpD,       // partial slots 0..255 (d_out, 64KB each)
    bf16_t* __restrict__ OpX,       // partial slots 256..319 (ws)
    float* __restrict__ lpart,      // 320 x 256 fp32
    int S)
{
    __shared__ __align__(16) bf16_t sK[2][64 * 136];   // 34.8 KB (dbuf)
    __shared__ __align__(16) bf16_t sVT[2][128 * 72];  // 36.9 KB (dbuf)
    __shared__ __align__(16) bf16_t sP[4][4][16 * 72]; // 36.9 KB, per wave+head

    const int c   = blockIdx.x;          // chunk 0..63
    const int kvh = blockIdx.y;
    const int p   = c >> 2, sub = c & 3; // pair p: qtA=p, qtB=31-p
    const int ts   = (33 * sub + 3) >> 2;    // chunk t-range [ts, tend)
    const int tend = (33 * sub + 36) >> 2;   // sizes 9,8,8,8 over t=0..32
    const int tA   = p + 1;                  // t < tA -> qtA, else qtB

    const int tid = threadIdx.x, lane = tid & 63, wave = tid >> 6;
    const int l16 = lane & 15, quad = lane >> 4;
    const int rowg = wave;                        // q-row group 0..3
    const int h0   = kvh * 4;                     // 4 heads per wave
    const float scale = 0.08838834764831845f;     // 1/sqrt(128)

    // staging: 1024 16B-chunks per tile, 256 threads -> 4 chunks each
    int krow[4], kcol[4], vrow[4], vcol[4];
#pragma unroll
    for (int it = 0; it < 4; it++) {
        int cc = tid + 256 * it;
        krow[it] = cc >> 4; kcol[it] = (cc & 15) * 8;
        vrow[it] = cc >> 3; vcol[it] = (cc & 7) * 8;
    }

#pragma unroll
    for (int sI = 0; sI < 2; sI++) {
        int st0, st1, sqt, ssl;
        if (sI == 0) {
            if (ts < tA) { st0 = ts; st1 = (tend < tA ? tend : tA); sqt = p;      ssl = c; }
            else         { st0 = ts; st1 = tend;                    sqt = 31 - p; ssl = c; }
        } else {
            if (!(ts < tA && tend > tA)) break;
            st0 = tA; st1 = tend; sqt = 31 - p; ssl = 64 + p;
        }
        const int base = (sqt == p) ? 0 : tA;   // kt = t - base
        const int kb = st0 - base, ke = st1 - base;
        const int qt = sqt;
        const int q0 = qt * 64;
        const int qrow = q0 + rowg * 16 + l16;

        // Q fragments: 4 heads (B-operand of swapped QK), then fused RoPE.
        bf16x8 qf[4][4];
#pragma unroll
        for (int h = 0; h < 4; h++)
#pragma unroll
            for (int cc = 0; cc < 4; cc++)
                qf[h][cc] = *(const bf16x8*)&Q[(size_t)qrow * HID + (h0 + h) * HD + cc * 32 + quad * 8];

        {
            // cos/sin for this thread's d-positions (same for all heads):
            // group 0: chunks (0,2), d = quad*8+e; group 1: chunks (1,3), d = 32+quad*8+e.
            float cs0[8], sn0[8], cs1[8], sn1[8];
            const float* cb = cosb + (size_t)qrow * HD;
            const float* sb = sinb + (size_t)qrow * HD;
#pragma unroll
            for (int e = 0; e < 8; e++) {
                cs0[e] = cb[quad * 8 + e];      sn0[e] = sb[quad * 8 + e];
                cs1[e] = cb[32 + quad * 8 + e]; sn1[e] = sb[32 + quad * 8 + e];
            }
#pragma unroll
            for (int h = 0; h < 4; h++) {
                bf16x8 lo0 = qf[h][0], hi0 = qf[h][2];
                bf16x8 lo1 = qf[h][1], hi1 = qf[h][3];
                bf16x8 a0, b0, a1, b1;
#pragma unroll
                for (int e = 0; e < 8; e += 2) {
                    float x0 = (float)lo0[e], x1 = (float)lo0[e + 1];
                    float p0 = (float)hi0[e], p1 = (float)hi0[e + 1];
                    a0[e]     = (bf16_t)(-x1 * cs0[e]     + p0 * sn0[e]);
                    a0[e + 1] = (bf16_t)( x0 * cs0[e + 1] + p1 * sn0[e + 1]);
                    b0[e]     = (bf16_t)( x1 * sn0[e]     + p0 * cs0[e]);
                    b0[e + 1] = (bf16_t)(-x0 * sn0[e + 1] + p1 * cs0[e + 1]);
                    float y0 = (float)lo1[e], y1 = (float)lo1[e + 1];
                    float q0v = (float)hi1[e], q1v = (float)hi1[e + 1];
                    a1[e]     = (bf16_t)(-y1 * cs1[e]     + q0v * sn1[e]);
                    a1[e + 1] = (bf16_t)( y0 * cs1[e + 1] + q1v * sn1[e + 1]);
                    b1[e]     = (bf16_t)( y1 * sn1[e]     + q0v * cs1[e]);
                    b1[e + 1] = (bf16_t)(-y0 * sn1[e + 1] + q1v * cs1[e + 1]);
                }
                qf[h][0] = a0; qf[h][2] = b0;
                qf[h][1] = a1; qf[h][3] = b1;
            }
        }

        f32x4 oacc[4][8] = {};
        float lsum[4] = {0.f, 0.f, 0.f, 0.f};

        // prologue: tile kb -> regs -> buf0; prefetch kb+1 into regs
        bf16x8 kpre[4], vpre[4];
#pragma unroll
        for (int it = 0; it < 4; it++) {
            kpre[it] = *(const bf16x8*)&Kb[(size_t)(kb * 64 + krow[it]) * (NKV * HD) + kvh * HD + kcol[it]];
            vpre[it] = *(const bf16x8*)&VT[((size_t)kvh * HD + vrow[it]) * S + kb * 64 + vcol[it]];
        }
#pragma unroll
        for (int it = 0; it < 4; it++) {
            *(bf16x8*)&sK[0][krow[it] * 136 + kcol[it]] = kpre[it];
            *(bf16x8*)&sVT[0][vrow[it] * 72 + vcol[it]] = vpre[it];
        }
        if (kb + 1 < ke) {
            const int t1 = (kb + 1) * 64;
#pragma unroll
            for (int it = 0; it < 4; it++) {
                kpre[it] = *(const bf16x8*)&Kb[(size_t)(t1 + krow[it]) * (NKV * HD) + kvh * HD + kcol[it]];
                vpre[it] = *(const bf16x8*)&VT[((size_t)kvh * HD + vrow[it]) * S + t1 + vcol[it]];
            }
        }
        __syncthreads();

        int sel = 0;
        for (int kt = kb; kt < ke; kt++) {
            const int t0 = kt * 64;
            const int ns = sel ^ 1;

            // stage tile kt+1 into the other buffers (overlaps compute)
            if (kt + 1 < ke) {
#pragma unroll
                for (int it = 0; it < 4; it++) {
                    *(bf16x8*)&sK[ns][krow[it] * 136 + kcol[it]] = kpre[it];
                    *(bf16x8*)&sVT[ns][vrow[it] * 72 + vcol[it]] = vpre[it];
                }
                if (kt + 2 < ke) {
                    const int t2 = t0 + 128;
#pragma unroll
                    for (int it = 0; it < 4; it++) {
                        kpre[it] = *(const bf16x8*)&Kb[(size_t)(t2 + krow[it]) * (NKV * HD) + kvh * HD + kcol[it]];
                        vpre[it] = *(const bf16x8*)&VT[((size_t)kvh * HD + vrow[it]) * S + t2 + vcol[it]];
                    }
                }
            }

            // ---- QK^T (swapped): nt outer, kf read once, 4 heads share ----
            f32x4 sc[4][4];   // [h][nt]
            __builtin_amdgcn_s_setprio(1);
#pragma unroll
            for (int nt = 0; nt < 4; nt++) {
                bf16x8 kf[4];
#pragma unroll
                for (int cc = 0; cc < 4; cc++)
                    kf[cc] = *(bf16x8*)&sK[sel][(nt * 16 + l16) * 136 + cc * 32 + quad * 8];
#pragma unroll
                for (int h = 0; h < 4; h++) {
                    f32x4 d = {};
#pragma unroll
                    for (int cc = 0; cc < 4; cc++)
                        d = __builtin_amdgcn_mfma_f32_16x16x32_bf16(kf[cc], qf[h][cc], d, 0, 0, 0);
                    sc[h][nt] = d;
                }
            }
            __builtin_amdgcn_s_setprio(0);

            // ---- exp + packed P writes (ALL heads), then batched reads ----
            if (kt == qt) {
#pragma unroll
                for (int h = 0; h < 4; h++)
#pragma unroll
                    for (int nt = 0; nt < 4; nt++) {
                        const int tbk = t0 + nt * 16 + quad * 4;
                        bf16x4 pk;
#pragma unroll
                        for (int r = 0; r < 4; r++) {
                            float pv = (tbk + r <= qrow) ? __expf(sc[h][nt][r] * scale) : 0.0f;
                            lsum[h] += pv;
                            pk[r] = (bf16_t)pv;
                        }
                        *(bf16x4*)&sP[wave][h][l16 * 72 + nt * 16 + quad * 4] = pk;
                    }
            } else {
#pragma unroll
                for (int h = 0; h < 4; h++)
#pragma unroll
                    for (int nt = 0; nt < 4; nt++) {
                        bf16x4 pk;
#pragma unroll
                        for (int r = 0; r < 4; r++) {
                            float pv = __expf(sc[h][nt][r] * scale);
                            lsum[h] += pv;
                            pk[r] = (bf16_t)pv;
                        }
                        *(bf16x4*)&sP[wave][h][l16 * 72 + nt * 16 + quad * 4] = pk;
                    }
            }
            bf16x8 pa[4][2];
#pragma unroll
            for (int h = 0; h < 4; h++)
#pragma unroll
                for (int kc = 0; kc < 2; kc++)
                    pa[h][kc] = *(bf16x8*)&sP[wave][h][l16 * 72 + kc * 32 + quad * 8];

            // ---- PV: dt outer, vf read once, 4 heads share it ----
            __builtin_amdgcn_s_setprio(1);
#pragma unroll
            for (int dt = 0; dt < 8; dt++)
#pragma unroll
                for (int kc = 0; kc < 2; kc++) {
                    bf16x8 vf = *(bf16x8*)&sVT[sel][(dt * 16 + l16) * 72 + kc * 32 + quad * 8];
#pragma unroll
                    for (int h = 0; h < 4; h++)
                        oacc[h][dt] = __builtin_amdgcn_mfma_f32_16x16x32_bf16(pa[h][kc], vf, oacc[h][dt], 0, 0, 0);
                }
            __builtin_amdgcn_s_setprio(0);

            __syncthreads();   // buf[ns] writes visible; buf[sel] reads done
            sel = ns;
        }

        // epilogue: store UNNORMALIZED partial O + partial l into slot sg.
        // Slot layout: [64 rows][4 local heads][128 cols] bf16 (64 KB).
        const int sg = kvh * 80 + ssl;
        bf16_t* Op = (sg < 256) ? (OpD + (size_t)sg * 32768)
                                : (OpX + (size_t)(sg - 256) * 32768);
#pragma unroll
        for (int h = 0; h < 4; h++) {
            float lr = lsum[h];
            lr += __shfl_xor(lr, 16, 64);
            lr += __shfl_xor(lr, 32, 64);   // lane L: l for row offset L&15
            if (quad == 0)
                lpart[(size_t)sg * 256 + (rowg * 16 + l16) * 4 + h] = lr;
#pragma unroll
            for (int r = 0; r < 4; r++) {
                int rr = rowg * 16 + quad * 4 + r;   // row within tile
#pragma unroll
                for (int dt = 0; dt < 8; dt++)
                    Op[((size_t)rr * 4 + h) * 128 + dt * 16 + l16] =
                        (bf16_t)(oacc[h][dt][r]);
            }
        }
    }
}

// ---------------------------------------------------------------------------
// Combine: oh[s,h,:] = (sum O_slot) / (sum l_slot) over the <=4 slots that
// contributed to q-tile qt = s>>6. Slot enumeration mirrors flash_attn12.
// ---------------------------------------------------------------------------
__global__ __launch_bounds__(256) void flash_combine10(
    const bf16_t* __restrict__ OpD, const bf16_t* __restrict__ OpX,
    const float* __restrict__ lpart, bf16_t* __restrict__ oh)
{
    int i = (blockIdx.x * 256 + threadIdx.x) * 8;
    int s = i >> 11;            // row (2048 cols)
    int h = (i >> 7) & 15;      // head
    int col = i & 127;
    int qt = s >> 6;
    int base80 = (h >> 2) * 80;
    int roff = (s & 63) * 4 + (h & 3);

    int sl[4]; int nsl = 0;
    if (qt <= 15) {
        int pr = qt;
#pragma unroll
        for (int sub = 0; sub < 4; sub++) {
            int tss = (33 * sub + 3) >> 2;
            if (tss < qt + 1) sl[nsl++] = pr * 4 + sub;
        }
    } else {
        int pr = 31 - qt, tAh = pr + 1;
#pragma unroll
        for (int sub = 0; sub < 4; sub++) {
            int tss = (33 * sub + 3) >> 2;
            int ten = (33 * sub + 36) >> 2;
            if (ten > tAh) sl[nsl++] = (tss < tAh) ? 64 + pr : pr * 4 + sub;
        }
    }

    float acc[8] = {0.f, 0.f, 0.f, 0.f, 0.f, 0.f, 0.f, 0.f};
    float l = 0.f;
    for (int ci = 0; ci < nsl; ci++) {
        int sg = base80 + sl[ci];
        const bf16_t* P = (sg < 256) ? (OpD + (size_t)sg * 32768)
                                     : (OpX + (size_t)(sg - 256) * 32768);
        bf16x8 a = *(const bf16x8*)&P[(size_t)roff * 128 + col];
#pragma unroll
        for (int j = 0; j < 8; j++) acc[j] += (float)a[j];
        l += lpart[(size_t)sg * 256 + roff];
    }
    float inv = 1.0f / l;
    bf16x8 o;
#pragma unroll
    for (int j = 0; j < 8; j++)
        o[j] = (bf16_t)(acc[j] * inv);
    *(bf16x8*)&oh[i] = o;
}

// ---------------------------------------------------------------------------
extern "C" void kernel_launch(void* const* d_in, const int* in_sizes, int n_in,
                              void* d_out, int out_size, void* d_ws, size_t ws_size,
                              hipStream_t stream)
{
    const float* x    = (const float*)d_in[0];
    const float* cosb = (const float*)d_in[1];
    const float* sinb = (const float*)d_in[2];
    const float* wq   = (const float*)d_in[3];
    const float* wk   = (const float*)d_in[4];
    const float* wv   = (const float*)d_in[5];
    const float* wo   = (const float*)d_in[6];
    float* out = (float*)d_out;

    // Workspace (32.5 MB of the 256 MB ws):
    char* ws = (char*)d_ws;
    bf16_t* wb = (bf16_t*)(ws);                              // 0..12 MB: [wq;wk;wv] bf16
    bf16_t* qh = (bf16_t*)(ws + (size_t)12 * 1024 * 1024);   // 12..20 MB: q / attn-out
    bf16_t* kh = (bf16_t*)(ws + (size_t)20 * 1024 * 1024);   // 20..22 MB: k
    bf16_t* vT = (bf16_t*)(ws + (size_t)22 * 1024 * 1024);   // 22..24 MB: v^T
    float*  lp = (float*) (ws + (size_t)24 * 1024 * 1024);   // 24..24.32 MB: partial l (320x256 f32)
    bf16_t* opx = (bf16_t*)(ws + (size_t)24 * 1024 * 1024 + 512 * 1024); // 24.5..28.5 MB: slots 256..319
    bf16_t* wob = (bf16_t*)(ws + (size_t)28 * 1024 * 1024 + 512 * 1024); // 28.5..32.5 MB: wo bf16
    // d_out (16 MB) doubles as scratch: x bf16 (steps 1-2), then partial
    // slots 0..255 (steps 4-5).
    bf16_t* xb  = (bf16_t*)d_out;
    bf16_t* opd = (bf16_t*)d_out;

    const int NX = S_LEN * HID;   // 4 Mi

    // 1) all fp32 -> bf16 conversions in one pass (x, wq|wk|wv, wo)
    cvt_all<<<14 * 1024 * 1024 / (256 * 8), 256, 0, stream>>>(
        x, wq, wk, wv, wo, xb, wb, wob);

    // 2) fused QKV GEMM (2-phase dbuf), routed outputs. 768 blocks = 3/CU.
    gemm128x64<1, bf16_t><<<dim3(48, 16), 256, 0, stream>>>(xb, wb, qh, kh, vT, 3072, HID);

    // 3) RoPE on k only (q-RoPE fused into attention)
    rope_k<<<dim3(S_LEN, 1), 128, 0, stream>>>(kh, cosb, sinb);

    // 4) flash attention v12: 4 waves x 4 heads + fused Q-RoPE, 256 blocks.
    flash_attn12<<<dim3(64, NKV), 256, 0, stream>>>(qh, kh, vT, cosb, sinb,
                                                    opd, opx, lp, S_LEN);

    // 5) combine partial slots -> qh (attn output, normalized bf16)
    flash_combine10<<<NX / (256 * 8), 256, 0, stream>>>(opd, opx, lp, qh);

    // 6) out = attn_out @ wo^T -> fp32 d_out (2-phase dbuf). 512 blocks = 2/CU.
    gemm128x64<0, float><<<dim3(32, 16), 256, 0, stream>>>(qh, wob, out, nullptr, nullptr, HID, HID);
}